// Round 14
// baseline (946.247 us; speedup 1.0000x reference)
//
#include <hip/hip_runtime.h>
#include <math.h>

typedef unsigned short u16;
typedef __attribute__((ext_vector_type(8))) short short8;
typedef __attribute__((ext_vector_type(8))) __bf16 bf16x8;
typedef __attribute__((ext_vector_type(4))) float f32x4;

#define FLAG_BIAS   1
#define FLAG_RES    2
#define FLAG_GELU   4
#define FLAG_TRI    8
#define FLAG_CK     16

__device__ __forceinline__ u16 f2bf(float f) {
  unsigned u = __builtin_bit_cast(unsigned, f);
  unsigned r = u + 0x7fffu + ((u >> 16) & 1u);   // RNE
  return (u16)(r >> 16);
}
__device__ __forceinline__ float bf2f(u16 u) {
  return __builtin_bit_cast(float, (unsigned)u << 16);
}
__device__ __forceinline__ float wred_sum(float v) {
#pragma unroll
  for (int m = 32; m; m >>= 1) v += __shfl_xor(v, m, 64);
  return v;
}
__device__ __forceinline__ float wred_max(float v) {
#pragma unroll
  for (int m = 32; m; m >>= 1) v = fmaxf(v, __shfl_xor(v, m, 64));
  return v;
}
// tanh-form GELU: max dev ~3e-3, below bf16 rounding of activations
__device__ __forceinline__ float gelu_fast(float x) {
  float y = 0.7978845608f * x * (1.f + 0.044715f * x * x);
  float e = __expf(2.f * y);
  float th = 1.f - 2.f / (e + 1.f);
  return 0.5f * x * (1.f + th);
}
__device__ __forceinline__ f32x4 mfma16(short8 a, short8 b, f32x4 c) {
  return __builtin_amdgcn_mfma_f32_16x16x32_bf16(
      __builtin_bit_cast(bf16x8, a), __builtin_bit_cast(bf16x8, b), c, 0, 0, 0);
}

#define GLOAD_LDS16(gptr, lptr)                                              \
  __builtin_amdgcn_global_load_lds(                                          \
      (const __attribute__((address_space(1))) void*)(gptr),                 \
      (__attribute__((address_space(3))) void*)(lptr), 16, 0, 0)

// ---------------------------------------------------------------------------
// m97-faithful 128x128 bt-GEMM: BK=64, 256 thr (4 waves 2x2, wave-tile
// 64x64, acc[4][4]=64 AGPR), SINGLE-buffered LDS 32KB -> with ~70 VGPR the
// budget is ~134/wave -> 3 waves/SIMD -> 3 BLOCKS/CU. Cross-block overlap
// (m114) hides the __syncthreads vmcnt-drain — this structure measured
// 874-912 TF on this toolchain (m97/m103). No asm, no pins, no setprio,
// no swizzle (m97's linear-LDS conflicts are non-binding); compiler emits
// fine-grained lgkmcnt scheduling (m97 asm evidence).
// XCD-aware bn-major order (B-panel L2-hot), optional causal-triangle
// grid (136 blocks/batch) / causal K-limit.
// C[M,N] = epi(alpha * A[M,K] @ B[N,K]^T)
// ---------------------------------------------------------------------------
__global__ __launch_bounds__(256, 3) void gemm128(
    const u16* __restrict__ Aptr, const u16* __restrict__ Bptr,
    u16* __restrict__ Cptr, const float* __restrict__ bias,
    const u16* __restrict__ resp,
    int M, int N, int K, int lda, int ldb, int ldc, float alpha, int flags,
    long long sA, long long sB, long long sC) {
  const int nwg = gridDim.x;
  const int cpx = nwg >> 3;                 // all grids %8 == 0
  const int bid = blockIdx.x;
  const int swz = (bid & 7) * cpx + (bid >> 3);
  int bm, bn, z;
  if (flags & FLAG_TRI) {                   // flat lower triangle, 16 rows
    z = swz / 136;
    int tq = swz - z * 136;
    bm = (int)((sqrtf(8.f * tq + 1.f) - 1.f) * 0.5f);
    while ((bm + 1) * (bm + 2) / 2 <= tq) ++bm;
    while (bm * (bm + 1) / 2 > tq) --bm;
    bn = tq - bm * (bm + 1) / 2;
  } else {                                  // bn-major: B-panel stays L2-hot
    z = blockIdx.z;
    const int nbm = M >> 7;
    bn = swz / nbm;
    bm = swz - bn * nbm;
  }
  const int gm0 = bm << 7, gn0 = bn << 7;
  const int kend = (flags & FLAG_CK) ? min(K, gm0 + 128) : K;

  __shared__ __align__(16) u16 As[128 * 64];
  __shared__ __align__(16) u16 Bs[128 * 64];

  const int t = threadIdx.x;
  const int l = t & 63;
  const int w = t >> 6;
  const int wr = w >> 1, wc = w & 1;        // 2x2 waves; wave-tile 64x64
  const int frow = l & 15;
  const int fk = (l >> 4) << 3;             // 0,8,16,24 (elements)

  // staging: 256 thr x 16B = 4KB = 32 rows x 128B per gload op; linear LDS
  const int srow = t >> 3;                  // 0..31
  const int scol = (t & 7) << 3;            // element col 0..56
  const u16* Ag = Aptr + (size_t)z * sA + (size_t)(gm0 + srow) * lda + scol;
  const u16* Bg = Bptr + (size_t)z * sB + (size_t)(gn0 + srow) * ldb + scol;

  f32x4 acc[4][4] = {};

  for (int kt = 0; kt < kend; kt += 64) {
#pragma unroll
    for (int j = 0; j < 4; ++j) {
      GLOAD_LDS16(Ag + (size_t)j * 32 * lda + kt, &As[j * 2048 + w * 512]);
      GLOAD_LDS16(Bg + (size_t)j * 32 * ldb + kt, &Bs[j * 2048 + w * 512]);
    }
    __syncthreads();
#pragma unroll
    for (int kk = 0; kk < 64; kk += 32) {
      short8 af[4], bf[4];
#pragma unroll
      for (int mt = 0; mt < 4; ++mt)
        af[mt] = *(const short8*)&As[(wr * 64 + mt * 16 + frow) * 64 + kk + fk];
#pragma unroll
      for (int nt = 0; nt < 4; ++nt)
        bf[nt] = *(const short8*)&Bs[(wc * 64 + nt * 16 + frow) * 64 + kk + fk];
#pragma unroll
      for (int mt = 0; mt < 4; ++mt)
#pragma unroll
        for (int nt = 0; nt < 4; ++nt)
          acc[mt][nt] = mfma16(af[mt], bf[nt], acc[mt][nt]);
    }
    __syncthreads();
  }

  u16* Cb = Cptr + (size_t)z * sC;
  const bool hasB = flags & FLAG_BIAS, hasR = flags & FLAG_RES;
  const bool doG = flags & FLAG_GELU;
#pragma unroll
  for (int mt = 0; mt < 4; ++mt) {
#pragma unroll
    for (int nt = 0; nt < 4; ++nt) {
      int row0 = gm0 + wr * 64 + mt * 16 + ((l >> 4) << 2);
      int col = gn0 + wc * 64 + nt * 16 + frow;
      float bv = hasB ? bias[col] : 0.0f;
#pragma unroll
      for (int i = 0; i < 4; ++i) {
        float v = acc[mt][nt][i] * alpha + bv;
        if (doG) v = gelu_fast(v);
        size_t idx = (size_t)(row0 + i) * ldc + col;
        if (hasR) v += bf2f(resp[idx]);
        Cb[idx] = f2bf(v);
      }
    }
  }
}

// ---------------------------------------------------------------------------
__global__ __launch_bounds__(256) void f32_to_bf16_v4(const float* __restrict__ in,
                                                      u16* __restrict__ out, int n4) {
  int i = blockIdx.x * 256 + threadIdx.x;
  if (i < n4) {
    float4 v = ((const float4*)in)[i];
    ushort4 o;
    o.x = f2bf(v.x); o.y = f2bf(v.y); o.z = f2bf(v.z); o.w = f2bf(v.w);
    ((ushort4*)out)[i] = o;
  }
}

// embed gather + LN1
__global__ __launch_bounds__(256) void embed_ln1(
    const int* __restrict__ x, const float* __restrict__ emb,
    const float* __restrict__ w, const float* __restrict__ b,
    u16* __restrict__ h16, u16* __restrict__ hn) {
  int row = blockIdx.x * 4 + (threadIdx.x >> 6);
  int lane = threadIdx.x & 63;
  int tok = x[row];
  const float* e = emb + (size_t)tok * 1024;
  float v[16];
  float s = 0.f, q = 0.f;
#pragma unroll
  for (int i = 0; i < 16; ++i) { v[i] = e[lane + i * 64]; s += v[i]; q += v[i] * v[i]; }
  s = wred_sum(s); q = wred_sum(q);
  float mu = s * (1.0f / 1024.0f);
  float rstd = rsqrtf(q * (1.0f / 1024.0f) - mu * mu + 1e-5f);
  u16* hr = h16 + (size_t)row * 1024;
  u16* hnr = hn + (size_t)row * 1024;
#pragma unroll
  for (int i = 0; i < 16; ++i) {
    int d = lane + i * 64;
    hr[d] = f2bf(v[i]);
    hnr[d] = f2bf((v[i] - mu) * rstd * w[d] + b[d]);
  }
}

__global__ __launch_bounds__(256) void ln_rows(
    const u16* __restrict__ in, const float* __restrict__ w,
    const float* __restrict__ b, u16* __restrict__ out) {
  int row = blockIdx.x * 4 + (threadIdx.x >> 6);
  int lane = threadIdx.x & 63;
  const short8* ir = (const short8*)(in + (size_t)row * 1024);
  short8 c0 = ir[lane], c1 = ir[lane + 64];
  float v[16];
  float s = 0.f, q = 0.f;
#pragma unroll
  for (int j = 0; j < 8; ++j) {
    v[j] = bf2f((u16)c0[j]); v[8 + j] = bf2f((u16)c1[j]);
  }
#pragma unroll
  for (int j = 0; j < 16; ++j) { s += v[j]; q += v[j] * v[j]; }
  s = wred_sum(s); q = wred_sum(q);
  float mu = s * (1.0f / 1024.0f);
  float rstd = rsqrtf(q * (1.0f / 1024.0f) - mu * mu + 1e-5f);
  short8 o0, o1;
#pragma unroll
  for (int j = 0; j < 8; ++j) {
    int d0 = lane * 8 + j, d1 = 512 + lane * 8 + j;
    o0[j] = (short)f2bf((v[j] - mu) * rstd * w[d0] + b[d0]);
    o1[j] = (short)f2bf((v[8 + j] - mu) * rstd * w[d1] + b[d1]);
  }
  short8* orow = (short8*)(out + (size_t)row * 1024);
  orow[lane] = o0; orow[lane + 64] = o1;
}

// in-place causal softmax, column-trimmed to ceil512(i+1)
__global__ __launch_bounds__(256) void softmax_causal(u16* att) {
  int r = blockIdx.x * 4 + (threadIdx.x >> 6);
  int lane = threadIdx.x & 63;
  int i = r & 2047;
  int n = i + 1;
  int ng = (i >> 9) + 1;
  short8* pv = (short8*)(att + (size_t)r * 2048);
  float v[32];
  float m = -1e30f;
#pragma unroll
  for (int g = 0; g < 4; ++g) {
    if (g < ng) {
      short8 c = pv[g * 64 + lane];
#pragma unroll
      for (int j = 0; j < 8; ++j) {
        int idx = g * 512 + lane * 8 + j;
        float f = (idx < n) ? bf2f((u16)c[j]) : -1e30f;
        v[g * 8 + j] = f;
        m = fmaxf(m, f);
      }
    }
  }
  m = wred_max(m);
  float s = 0.f;
#pragma unroll
  for (int g = 0; g < 4; ++g) {
    if (g < ng) {
#pragma unroll
      for (int j = 0; j < 8; ++j) {
        int idx = g * 512 + lane * 8 + j;
        float e = (idx < n) ? __expf(v[g * 8 + j] - m) : 0.f;
        v[g * 8 + j] = e; s += e;
      }
    }
  }
  s = wred_sum(s);
  float inv = 1.0f / s;
#pragma unroll
  for (int g = 0; g < 4; ++g) {
    if (g < ng) {
      short8 o;
#pragma unroll
      for (int j = 0; j < 8; ++j) o[j] = (short)f2bf(v[g * 8 + j] * inv);
      pv[g * 64 + lane] = o;
    }
  }
}

// V (strided ldv) [z][2048][*] -> Vt [z][1024][2048]
__global__ __launch_bounds__(256) void transpose_v(const u16* __restrict__ V,
                                                   u16* __restrict__ Vt, int ldv) {
  int z = blockIdx.z;
  const u16* src = V + (size_t)z * 2048 * ldv;
  u16* dst = Vt + (size_t)z * 1024 * 2048;
  int j0 = (blockIdx.x >> 4) << 6;
  int d0 = (blockIdx.x & 15) << 6;
  __shared__ u16 tile[64][65];
  int c = threadIdx.x & 15;
  int rr = threadIdx.x >> 4;
#pragma unroll
  for (int q = 0; q < 4; ++q) {
    int row = rr + q * 16;
    ushort4 val = *(const ushort4*)(src + (size_t)(j0 + row) * ldv + d0 + c * 4);
    tile[row][c * 4 + 0] = val.x; tile[row][c * 4 + 1] = val.y;
    tile[row][c * 4 + 2] = val.z; tile[row][c * 4 + 3] = val.w;
  }
  __syncthreads();
#pragma unroll
  for (int q = 0; q < 4; ++q) {
    int drow = rr + q * 16;
    ushort4 o;
    o.x = tile[c * 4 + 0][drow]; o.y = tile[c * 4 + 1][drow];
    o.z = tile[c * 4 + 2][drow]; o.w = tile[c * 4 + 3][drow];
    *(ushort4*)(dst + (size_t)(d0 + drow) * 2048 + j0 + c * 4) = o;
  }
}

// final LN + logits (N=14), emb staged in padded LDS
__global__ __launch_bounds__(256) void lnf_logits(
    const u16* __restrict__ h, const float* __restrict__ w,
    const float* __restrict__ b, const float* __restrict__ emb,
    float* __restrict__ out) {
  __shared__ float el[14 * 1056];
  int t = threadIdx.x;
  for (int f = t * 4; f < 14 * 1024; f += 1024) {
    float4 e = *(const float4*)(emb + f);
    int v = f >> 10, d = f & 1023;
    float* dst = el + v * 1056 + d + (d >> 5);
    dst[0] = e.x; dst[1] = e.y; dst[2] = e.z; dst[3] = e.w;
  }
  __syncthreads();
  int lane = t & 63, wid = t >> 6;
  float w0[8], w1[8], b0[8], b1[8];
#pragma unroll
  for (int j = 0; j < 8; ++j) {
    int d0 = lane * 8 + j, d1 = 512 + lane * 8 + j;
    w0[j] = w[d0]; b0[j] = b[d0];
    w1[j] = w[d1]; b1[j] = b[d1];
  }
  const float* e0 = el + lane * 8 + (lane >> 2);
  const float* e1 = el + 528 + lane * 8 + (lane >> 2);
  for (int rr = 0; rr < 8; ++rr) {
    int row = blockIdx.x * 32 + wid * 8 + rr;
    const short8* hr = (const short8*)(h + (size_t)row * 1024);
    short8 c0 = hr[lane], c1 = hr[lane + 64];
    float v0[8], v1[8];
    float s = 0.f, q = 0.f;
#pragma unroll
    for (int j = 0; j < 8; ++j) {
      v0[j] = bf2f((u16)c0[j]); v1[j] = bf2f((u16)c1[j]);
      s += v0[j] + v1[j];
      q += v0[j] * v0[j] + v1[j] * v1[j];
    }
    s = wred_sum(s); q = wred_sum(q);
    float mu = s * (1.0f / 1024.0f);
    float rstd = rsqrtf(q * (1.0f / 1024.0f) - mu * mu + 1e-5f);
    float h0[8], h1[8];
#pragma unroll
    for (int j = 0; j < 8; ++j) {
      h0[j] = (v0[j] - mu) * rstd * w0[j] + b0[j];
      h1[j] = (v1[j] - mu) * rstd * w1[j] + b1[j];
    }
    float p[14];
#pragma unroll
    for (int v = 0; v < 14; ++v) {
      const float* ev0 = e0 + v * 1056;
      const float* ev1 = e1 + v * 1056;
      float a = 0.f;
#pragma unroll
      for (int j = 0; j < 8; ++j) a += h0[j] * ev0[j] + h1[j] * ev1[j];
      p[v] = a;
    }
#pragma unroll
    for (int m = 32; m; m >>= 1)
#pragma unroll
      for (int v = 0; v < 14; ++v) p[v] += __shfl_xor(p[v], m, 64);
    if (lane == 0) {
      float* orow = out + (size_t)row * 14;
#pragma unroll
      for (int v = 0; v < 14; ++v) orow[v] = p[v];
    }
  }
}

__global__ void zero_out_k(float* o, int n) {
  int i = blockIdx.x * 256 + threadIdx.x;
  if (i < n) o[i] = 0.f;
}
__global__ void diag_k(float* o, float v) { if (threadIdx.x == 0) o[0] = v; }

// ---------------------------------------------------------------------------
extern "C" void kernel_launch(void* const* d_in, const int* in_sizes, int n_in,
                              void* d_out, int out_size, void* d_ws, size_t ws_size,
                              hipStream_t stream) {
  const int* x = (const int*)d_in[0];
  const float* tok_emb = (const float*)d_in[1];
  const float* ln1_w = (const float*)d_in[2];
  const float* ln1_b = (const float*)d_in[3];
  const float* qw = (const float*)d_in[4];
  const float* qb = (const float*)d_in[5];
  const float* kw = (const float*)d_in[6];
  const float* kb = (const float*)d_in[7];
  const float* vw = (const float*)d_in[8];
  const float* vb = (const float*)d_in[9];
  const float* pw = (const float*)d_in[10];
  const float* pb = (const float*)d_in[11];
  const float* ln2_w = (const float*)d_in[12];
  const float* ln2_b = (const float*)d_in[13];
  const float* f1w = (const float*)d_in[14];
  const float* f1b = (const float*)d_in[15];
  const float* f2w = (const float*)d_in[16];
  const float* f2b = (const float*)d_in[17];
  const float* lnf_w = (const float*)d_in[18];
  const float* lnf_b = (const float*)d_in[19];
  float* out = (float*)d_out;

  const long long T = 16384, D = 1024, F = 4096, S = 2048;
  const size_t MB = 1ull << 20;
  char* base = (char*)d_ws;

  if (ws_size < 224 * MB) {
    zero_out_k<<<dim3((out_size + 255) / 256), 256, 0, stream>>>(out, out_size);
    diag_k<<<dim3(1), 1, 0, stream>>>(out, (float)ws_size);
    return;
  }

  // ---- 224 MB phase-multiplexed layout ----
  u16* rA16 = (u16*)base;                  // 0..32MB   residual bf16
  u16* rB   = (u16*)(base + 32 * MB);      // 32..64MB  normalized / Vt
  u16* QKV  = (u16*)(base + 64 * MB);      // 64..160MB [16384][3072] / CB
  u16* SC   = (u16*)(base + 160 * MB);     // 160..224MB W3+qkvb -> scores -> PW
  u16* W3   = SC;                          // [3072][1024] bf16 (6MB)
  float* qkvb = (float*)(base + 166 * MB); // 12KB
  u16* PW  = SC;                           // pw bf16 (2MB), post-PV
  u16* CB  = QKV;                          // [16384][4096] bf16, FFN
  u16* F1  = (u16*)(base + 192 * MB);      // [4096][1024] (8MB)
  u16* F2  = (u16*)(base + 200 * MB);      // [1024][4096] (8MB)

  auto cvt = [&](const float* src, u16* dst, long long n) {
    int n4 = (int)(n / 4);
    f32_to_bf16_v4<<<dim3((n4 + 255) / 256), dim3(256), 0, stream>>>(src, dst, n4);
  };
  auto gemm = [&](const u16* A, const u16* B, u16* C, const float* bias,
                  const u16* res, long long M, long long N, long long K,
                  long long lda, long long ldb, long long ldc, float alpha,
                  int flags, long long sA, long long sB, long long sC,
                  int gx, int gz) {
    gemm128<<<dim3(gx, 1, gz), dim3(256), 0, stream>>>(
        A, B, C, bias, res, (int)M, (int)N, (int)K, (int)lda, (int)ldb,
        (int)ldc, alpha, flags, sA, sB, sC);
  };

  // phase 0: fused QKV weights + biases into SC region (dead until scores)
  cvt(qw, W3, D * D);
  cvt(kw, W3 + 1024 * 1024, D * D);
  cvt(vw, W3 + 2 * 1024 * 1024, D * D);
  hipMemcpyAsync(qkvb, qb, D * 4, hipMemcpyDeviceToDevice, stream);
  hipMemcpyAsync(qkvb + 1024, kb, D * 4, hipMemcpyDeviceToDevice, stream);
  hipMemcpyAsync(qkvb + 2048, vb, D * 4, hipMemcpyDeviceToDevice, stream);

  embed_ln1<<<dim3(T / 4), 256, 0, stream>>>(x, tok_emb, ln1_w, ln1_b, rA16, rB);

  // fused QKV projection: [16384][3072]  grid 128x24 = 3072
  gemm(rB, W3, QKV, qkvb, nullptr, T, 3072, D, D, D, 3072, 1.f, FLAG_BIAS,
       0, 0, 0, 3072, 1);

  // scores = (Q K^T)/32, flat causal triangle (136 blocks x 8 batches)
  gemm(QKV, QKV + 1024, SC, nullptr, nullptr, S, S, D, 3072, 3072, 2048,
       0.03125f, FLAG_TRI, S * 3072, S * 3072, S * S, 1088, 1);

  // V^T per batch into rB (rB dead after QKV gemm)
  transpose_v<<<dim3(512, 1, 8), 256, 0, stream>>>(QKV + 2048, rB, 3072);

  softmax_causal<<<dim3(T / 4), 256, 0, stream>>>(SC);

  // attn out = P @ V^T, causal K-limit, into dead Q columns (16x8 grid x8)
  gemm(SC, rB, QKV, nullptr, nullptr, S, D, S, S, S, 3072, 1.f, FLAG_CK,
       S * S, D * S, S * 3072, 128, 8);

  // out-proj + residual (scores dead -> PW at SC)
  cvt(pw, PW, D * D);
  gemm(QKV, PW, rA16, pb, rA16, T, D, D, 3072, D, D, 1.f, FLAG_BIAS | FLAG_RES,
       0, 0, 0, 1024, 1);

  ln_rows<<<dim3(T / 4), 256, 0, stream>>>(rA16, ln2_w, ln2_b, rB);

  // FFN single-pass: CB [16384][4096] over dead QKV region
  cvt(f1w, F1, F * D);
  cvt(f2w, F2, D * F);
  gemm(rB, F1, CB, f1b, nullptr, T, F, D, D, D, F, 1.f, FLAG_BIAS | FLAG_GELU,
       0, 0, 0, 4096, 1);
  gemm(CB, F2, rA16, f2b, rA16, T, D, F, F, F, D, 1.f, FLAG_BIAS | FLAG_RES,
       0, 0, 0, 1024, 1);

  lnf_logits<<<dim3(512), 256, 0, stream>>>(rA16, lnf_w, lnf_b, tok_emb, out);
}

// Round 15
// 806.343 us; speedup vs baseline: 1.1735x; 1.1735x over previous
//
#include <hip/hip_runtime.h>
#include <math.h>

typedef unsigned short u16;
typedef __attribute__((ext_vector_type(8))) short short8;
typedef __attribute__((ext_vector_type(8))) __bf16 bf16x8;
typedef __attribute__((ext_vector_type(4))) float f32x4;

#define FLAG_BIAS   1
#define FLAG_RES    2
#define FLAG_GELU   4
#define FLAG_TRI    8
#define FLAG_CK     16

__device__ __forceinline__ u16 f2bf(float f) {
  unsigned u = __builtin_bit_cast(unsigned, f);
  unsigned r = u + 0x7fffu + ((u >> 16) & 1u);   // RNE
  return (u16)(r >> 16);
}
__device__ __forceinline__ float bf2f(u16 u) {
  return __builtin_bit_cast(float, (unsigned)u << 16);
}
__device__ __forceinline__ float wred_sum(float v) {
#pragma unroll
  for (int m = 32; m; m >>= 1) v += __shfl_xor(v, m, 64);
  return v;
}
__device__ __forceinline__ float wred_max(float v) {
#pragma unroll
  for (int m = 32; m; m >>= 1) v = fmaxf(v, __shfl_xor(v, m, 64));
  return v;
}
// tanh-form GELU: max dev ~3e-3, below bf16 rounding of activations
__device__ __forceinline__ float gelu_fast(float x) {
  float y = 0.7978845608f * x * (1.f + 0.044715f * x * x);
  float e = __expf(2.f * y);
  float th = 1.f - 2.f / (e + 1.f);
  return 0.5f * x * (1.f + th);
}
__device__ __forceinline__ f32x4 mfma16(short8 a, short8 b, f32x4 c) {
  return __builtin_amdgcn_mfma_f32_16x16x32_bf16(
      __builtin_bit_cast(bf16x8, a), __builtin_bit_cast(bf16x8, b), c, 0, 0, 0);
}

#define GLOAD_LDS16(gptr, lptr)                                              \
  __builtin_amdgcn_global_load_lds(                                          \
      (const __attribute__((address_space(1))) void*)(gptr),                 \
      (__attribute__((address_space(3))) void*)(lptr), 16, 0, 0)

// ---------------------------------------------------------------------------
// 256x256 bt-GEMM, BK=64, 512 thr (8 waves 2Mx4N, wave-tile 128x64),
// double-buffered LDS [2][256*64] per operand = 128KB. MINIMAL-SYNC (r11,
// best measured): one vmcnt(0) + one raw s_barrier per K-tile, no
// lgkmcnt/sched_barrier pins (m141). Conflict-free chunk-XOR swizzle.
// NEW (r15): 4x4 SUPERTILE block ordering — 16 consecutive swz share a
// 2MB A-slab + 2MB B-slab (= one XCD L2); supertiles walk st_m fast so
// the B-slab stays resident across the XCD's column. r11 measured 6.75x
// L2-miss over-fetch (FETCH 270MB vs 40MB unique) with per-tile fetch on
// the critical path — this ordering attacks that directly.
// NOTE: no __launch_bounds__ min-waves (r8 spill disaster).
// C[M,N] = epi(alpha * A[M,K] @ B[N,K]^T)
// ---------------------------------------------------------------------------
__global__ __launch_bounds__(512) void gemm256(
    const u16* __restrict__ Aptr, const u16* __restrict__ Bptr,
    u16* __restrict__ Cptr, const float* __restrict__ bias,
    const u16* __restrict__ resp,
    int M, int N, int K, int lda, int ldb, int ldc, float alpha, int flags,
    long long sA, long long sB, long long sC) {
  const int nwg = gridDim.x;
  const int cpx = nwg >> 3;                 // all grids %8 == 0
  const int bid = blockIdx.x;
  const int swz = (bid & 7) * cpx + (bid >> 3);
  int bm, bn, z;
  if (flags & FLAG_TRI) {                   // flat lower triangle (8 rows) + z
    z = swz / 36;
    int tq = swz - z * 36;
    bm = (int)((sqrtf(8.f * tq + 1.f) - 1.f) * 0.5f);
    while ((bm + 1) * (bm + 2) / 2 <= tq) ++bm;
    while (bm * (bm + 1) / 2 > tq) --bm;
    bn = tq - bm * (bm + 1) / 2;
  } else {
    // 4x4 supertile decode: 16 consecutive swz share A-slab+B-slab (4MB);
    // supertiles column-major (st_m fast) -> B-slab L2-resident per XCD.
    z = blockIdx.z;
    const int nbm = M >> 8;                 // %4 == 0 for all our shapes
    const int nsm = nbm >> 2;
    const int s = swz >> 4, lcl = swz & 15;
    const int stm = s % nsm, stn = s / nsm;
    bm = stm * 4 + (lcl >> 2);
    bn = stn * 4 + (lcl & 3);
  }
  const int gm0 = bm << 8, gn0 = bn << 8;
  const int kend = (flags & FLAG_CK) ? min(K, gm0 + 256) : K;
  const int NT = kend >> 6;                 // K-tiles of 64

  __shared__ __align__(16) u16 As[2][256 * 64];
  __shared__ __align__(16) u16 Bs[2][256 * 64];

  const int t = threadIdx.x;
  const int l = t & 63;
  const int w = t >> 6;                     // wave 0..7
  const int wr = w >> 2, wc = w & 3;        // 2M x 4N; wave-tile 128x64
  const int frow = l & 15;
  const int g4 = l >> 4;                    // k-quarter 0..3

  // staging: op j covers rows j*64 + (t>>3); 8 chunks of 16B per 128B row;
  // source chunk pre-swizzled by row&7 (read side XORs the same key)
  const int srow = t >> 3;                  // 0..63
  const int sch = (t & 7) ^ (srow & 7);
  const u16* Ag = Aptr + (size_t)z * sA + (size_t)(gm0 + srow) * lda + sch * 8;
  const u16* Bg = Bptr + (size_t)z * sB + (size_t)(gn0 + srow) * ldb + sch * 8;

  auto SA = [&](int buf, int j, int kt) {
    GLOAD_LDS16(Ag + (size_t)j * 64 * lda + kt, &As[buf][j * 4096 + w * 512]);
  };
  auto SB = [&](int buf, int j, int kt) {
    GLOAD_LDS16(Bg + (size_t)j * 64 * ldb + kt, &Bs[buf][j * 4096 + w * 512]);
  };

  f32x4 acc[8][4] = {};

  // prologue: tile 0 fully staged
#pragma unroll
  for (int j = 0; j < 4; ++j) { SA(0, j, 0); SB(0, j, 0); }
  asm volatile("s_waitcnt vmcnt(0)" ::: "memory");
  __builtin_amdgcn_s_barrier();
  asm volatile("" ::: "memory");

  for (int tt = 0; tt < NT; ++tt) {
    const int buf = tt & 1;
    const int ktn = (tt + 1) << 6;
    const bool pre = (tt + 1) < NT;
    short8 af[8], bf[4];

    // ===== kk = 0 =====
#pragma unroll
    for (int m = 0; m < 8; ++m) {
      int rr = wr * 128 + m * 16 + frow;
      af[m] = *(const short8*)&As[buf][rr * 64 + ((g4 ^ (rr & 7)) << 3)];
    }
#pragma unroll
    for (int n = 0; n < 4; ++n) {
      int rr = wc * 64 + n * 16 + frow;
      bf[n] = *(const short8*)&Bs[buf][rr * 64 + ((g4 ^ (rr & 7)) << 3)];
    }
    if (pre) {
#pragma unroll
      for (int j = 0; j < 4; ++j) SA(buf ^ 1, j, ktn);
    }
#pragma unroll
    for (int m = 0; m < 8; ++m)
#pragma unroll
      for (int n = 0; n < 4; ++n)
        acc[m][n] = mfma16(af[m], bf[n], acc[m][n]);

    // ===== kk = 32 (chunk index 4+g4) =====
#pragma unroll
    for (int m = 0; m < 8; ++m) {
      int rr = wr * 128 + m * 16 + frow;
      af[m] = *(const short8*)&As[buf][rr * 64 + (((4 + g4) ^ (rr & 7)) << 3)];
    }
#pragma unroll
    for (int n = 0; n < 4; ++n) {
      int rr = wc * 64 + n * 16 + frow;
      bf[n] = *(const short8*)&Bs[buf][rr * 64 + (((4 + g4) ^ (rr & 7)) << 3)];
    }
    if (pre) {
#pragma unroll
      for (int j = 0; j < 4; ++j) SB(buf ^ 1, j, ktn);
    }
#pragma unroll
    for (int m = 0; m < 8; ++m)
#pragma unroll
      for (int n = 0; n < 4; ++n)
        acc[m][n] = mfma16(af[m], bf[n], acc[m][n]);

    // single sync point per K-tile: own stages drained, then barrier
    asm volatile("s_waitcnt vmcnt(0)" ::: "memory");
    __builtin_amdgcn_s_barrier();
    asm volatile("" ::: "memory");
  }

  u16* Cb = Cptr + (size_t)z * sC;
  const bool hasB = flags & FLAG_BIAS, hasR = flags & FLAG_RES;
  const bool doG = flags & FLAG_GELU;
#pragma unroll
  for (int m = 0; m < 8; ++m) {
#pragma unroll
    for (int n = 0; n < 4; ++n) {
      int row0 = gm0 + wr * 128 + m * 16 + ((l >> 4) << 2);
      int col = gn0 + wc * 64 + n * 16 + frow;
      float bv = hasB ? bias[col] : 0.0f;
#pragma unroll
      for (int i = 0; i < 4; ++i) {
        float v = acc[m][n][i] * alpha + bv;
        if (doG) v = gelu_fast(v);
        size_t idx = (size_t)(row0 + i) * ldc + col;
        if (hasR) v += bf2f(resp[idx]);
        Cb[idx] = f2bf(v);
      }
    }
  }
}

// ---------------------------------------------------------------------------
__global__ __launch_bounds__(256) void f32_to_bf16_v4(const float* __restrict__ in,
                                                      u16* __restrict__ out, int n4) {
  int i = blockIdx.x * 256 + threadIdx.x;
  if (i < n4) {
    float4 v = ((const float4*)in)[i];
    ushort4 o;
    o.x = f2bf(v.x); o.y = f2bf(v.y); o.z = f2bf(v.z); o.w = f2bf(v.w);
    ((ushort4*)out)[i] = o;
  }
}

// embed gather + LN1
__global__ __launch_bounds__(256) void embed_ln1(
    const int* __restrict__ x, const float* __restrict__ emb,
    const float* __restrict__ w, const float* __restrict__ b,
    u16* __restrict__ h16, u16* __restrict__ hn) {
  int row = blockIdx.x * 4 + (threadIdx.x >> 6);
  int lane = threadIdx.x & 63;
  int tok = x[row];
  const float* e = emb + (size_t)tok * 1024;
  float v[16];
  float s = 0.f, q = 0.f;
#pragma unroll
  for (int i = 0; i < 16; ++i) { v[i] = e[lane + i * 64]; s += v[i]; q += v[i] * v[i]; }
  s = wred_sum(s); q = wred_sum(q);
  float mu = s * (1.0f / 1024.0f);
  float rstd = rsqrtf(q * (1.0f / 1024.0f) - mu * mu + 1e-5f);
  u16* hr = h16 + (size_t)row * 1024;
  u16* hnr = hn + (size_t)row * 1024;
#pragma unroll
  for (int i = 0; i < 16; ++i) {
    int d = lane + i * 64;
    hr[d] = f2bf(v[i]);
    hnr[d] = f2bf((v[i] - mu) * rstd * w[d] + b[d]);
  }
}

__global__ __launch_bounds__(256) void ln_rows(
    const u16* __restrict__ in, const float* __restrict__ w,
    const float* __restrict__ b, u16* __restrict__ out) {
  int row = blockIdx.x * 4 + (threadIdx.x >> 6);
  int lane = threadIdx.x & 63;
  const short8* ir = (const short8*)(in + (size_t)row * 1024);
  short8 c0 = ir[lane], c1 = ir[lane + 64];
  float v[16];
  float s = 0.f, q = 0.f;
#pragma unroll
  for (int j = 0; j < 8; ++j) {
    v[j] = bf2f((u16)c0[j]); v[8 + j] = bf2f((u16)c1[j]);
  }
#pragma unroll
  for (int j = 0; j < 16; ++j) { s += v[j]; q += v[j] * v[j]; }
  s = wred_sum(s); q = wred_sum(q);
  float mu = s * (1.0f / 1024.0f);
  float rstd = rsqrtf(q * (1.0f / 1024.0f) - mu * mu + 1e-5f);
  short8 o0, o1;
#pragma unroll
  for (int j = 0; j < 8; ++j) {
    int d0 = lane * 8 + j, d1 = 512 + lane * 8 + j;
    o0[j] = (short)f2bf((v[j] - mu) * rstd * w[d0] + b[d0]);
    o1[j] = (short)f2bf((v[8 + j] - mu) * rstd * w[d1] + b[d1]);
  }
  short8* orow = (short8*)(out + (size_t)row * 1024);
  orow[lane] = o0; orow[lane + 64] = o1;
}

// in-place causal softmax, column-trimmed to ceil512(i+1)
__global__ __launch_bounds__(256) void softmax_causal(u16* att) {
  int r = blockIdx.x * 4 + (threadIdx.x >> 6);
  int lane = threadIdx.x & 63;
  int i = r & 2047;
  int n = i + 1;
  int ng = (i >> 9) + 1;
  short8* pv = (short8*)(att + (size_t)r * 2048);
  float v[32];
  float m = -1e30f;
#pragma unroll
  for (int g = 0; g < 4; ++g) {
    if (g < ng) {
      short8 c = pv[g * 64 + lane];
#pragma unroll
      for (int j = 0; j < 8; ++j) {
        int idx = g * 512 + lane * 8 + j;
        float f = (idx < n) ? bf2f((u16)c[j]) : -1e30f;
        v[g * 8 + j] = f;
        m = fmaxf(m, f);
      }
    }
  }
  m = wred_max(m);
  float s = 0.f;
#pragma unroll
  for (int g = 0; g < 4; ++g) {
    if (g < ng) {
#pragma unroll
      for (int j = 0; j < 8; ++j) {
        int idx = g * 512 + lane * 8 + j;
        float e = (idx < n) ? __expf(v[g * 8 + j] - m) : 0.f;
        v[g * 8 + j] = e; s += e;
      }
    }
  }
  s = wred_sum(s);
  float inv = 1.0f / s;
#pragma unroll
  for (int g = 0; g < 4; ++g) {
    if (g < ng) {
      short8 o;
#pragma unroll
      for (int j = 0; j < 8; ++j) o[j] = (short)f2bf(v[g * 8 + j] * inv);
      pv[g * 64 + lane] = o;
    }
  }
}

// V (strided ldv) [z][2048][*] -> Vt [z][1024][2048]
__global__ __launch_bounds__(256) void transpose_v(const u16* __restrict__ V,
                                                   u16* __restrict__ Vt, int ldv) {
  int z = blockIdx.z;
  const u16* src = V + (size_t)z * 2048 * ldv;
  u16* dst = Vt + (size_t)z * 1024 * 2048;
  int j0 = (blockIdx.x >> 4) << 6;
  int d0 = (blockIdx.x & 15) << 6;
  __shared__ u16 tile[64][65];
  int c = threadIdx.x & 15;
  int rr = threadIdx.x >> 4;
#pragma unroll
  for (int q = 0; q < 4; ++q) {
    int row = rr + q * 16;
    ushort4 val = *(const ushort4*)(src + (size_t)(j0 + row) * ldv + d0 + c * 4);
    tile[row][c * 4 + 0] = val.x; tile[row][c * 4 + 1] = val.y;
    tile[row][c * 4 + 2] = val.z; tile[row][c * 4 + 3] = val.w;
  }
  __syncthreads();
#pragma unroll
  for (int q = 0; q < 4; ++q) {
    int drow = rr + q * 16;
    ushort4 o;
    o.x = tile[c * 4 + 0][drow]; o.y = tile[c * 4 + 1][drow];
    o.z = tile[c * 4 + 2][drow]; o.w = tile[c * 4 + 3][drow];
    *(ushort4*)(dst + (size_t)(d0 + drow) * 2048 + j0 + c * 4) = o;
  }
}

// final LN + logits (N=14), emb staged in padded LDS
__global__ __launch_bounds__(256) void lnf_logits(
    const u16* __restrict__ h, const float* __restrict__ w,
    const float* __restrict__ b, const float* __restrict__ emb,
    float* __restrict__ out) {
  __shared__ float el[14 * 1056];
  int t = threadIdx.x;
  for (int f = t * 4; f < 14 * 1024; f += 1024) {
    float4 e = *(const float4*)(emb + f);
    int v = f >> 10, d = f & 1023;
    float* dst = el + v * 1056 + d + (d >> 5);
    dst[0] = e.x; dst[1] = e.y; dst[2] = e.z; dst[3] = e.w;
  }
  __syncthreads();
  int lane = t & 63, wid = t >> 6;
  float w0[8], w1[8], b0[8], b1[8];
#pragma unroll
  for (int j = 0; j < 8; ++j) {
    int d0 = lane * 8 + j, d1 = 512 + lane * 8 + j;
    w0[j] = w[d0]; b0[j] = b[d0];
    w1[j] = w[d1]; b1[j] = b[d1];
  }
  const float* e0 = el + lane * 8 + (lane >> 2);
  const float* e1 = el + 528 + lane * 8 + (lane >> 2);
  for (int rr = 0; rr < 8; ++rr) {
    int row = blockIdx.x * 32 + wid * 8 + rr;
    const short8* hr = (const short8*)(h + (size_t)row * 1024);
    short8 c0 = hr[lane], c1 = hr[lane + 64];
    float v0[8], v1[8];
    float s = 0.f, q = 0.f;
#pragma unroll
    for (int j = 0; j < 8; ++j) {
      v0[j] = bf2f((u16)c0[j]); v1[j] = bf2f((u16)c1[j]);
      s += v0[j] + v1[j];
      q += v0[j] * v0[j] + v1[j] * v1[j];
    }
    s = wred_sum(s); q = wred_sum(q);
    float mu = s * (1.0f / 1024.0f);
    float rstd = rsqrtf(q * (1.0f / 1024.0f) - mu * mu + 1e-5f);
    float h0[8], h1[8];
#pragma unroll
    for (int j = 0; j < 8; ++j) {
      h0[j] = (v0[j] - mu) * rstd * w0[j] + b0[j];
      h1[j] = (v1[j] - mu) * rstd * w1[j] + b1[j];
    }
    float p[14];
#pragma unroll
    for (int v = 0; v < 14; ++v) {
      const float* ev0 = e0 + v * 1056;
      const float* ev1 = e1 + v * 1056;
      float a = 0.f;
#pragma unroll
      for (int j = 0; j < 8; ++j) a += h0[j] * ev0[j] + h1[j] * ev1[j];
      p[v] = a;
    }
#pragma unroll
    for (int m = 32; m; m >>= 1)
#pragma unroll
      for (int v = 0; v < 14; ++v) p[v] += __shfl_xor(p[v], m, 64);
    if (lane == 0) {
      float* orow = out + (size_t)row * 14;
#pragma unroll
      for (int v = 0; v < 14; ++v) orow[v] = p[v];
    }
  }
}

__global__ void zero_out_k(float* o, int n) {
  int i = blockIdx.x * 256 + threadIdx.x;
  if (i < n) o[i] = 0.f;
}
__global__ void diag_k(float* o, float v) { if (threadIdx.x == 0) o[0] = v; }

// ---------------------------------------------------------------------------
extern "C" void kernel_launch(void* const* d_in, const int* in_sizes, int n_in,
                              void* d_out, int out_size, void* d_ws, size_t ws_size,
                              hipStream_t stream) {
  const int* x = (const int*)d_in[0];
  const float* tok_emb = (const float*)d_in[1];
  const float* ln1_w = (const float*)d_in[2];
  const float* ln1_b = (const float*)d_in[3];
  const float* qw = (const float*)d_in[4];
  const float* qb = (const float*)d_in[5];
  const float* kw = (const float*)d_in[6];
  const float* kb = (const float*)d_in[7];
  const float* vw = (const float*)d_in[8];
  const float* vb = (const float*)d_in[9];
  const float* pw = (const float*)d_in[10];
  const float* pb = (const float*)d_in[11];
  const float* ln2_w = (const float*)d_in[12];
  const float* ln2_b = (const float*)d_in[13];
  const float* f1w = (const float*)d_in[14];
  const float* f1b = (const float*)d_in[15];
  const float* f2w = (const float*)d_in[16];
  const float* f2b = (const float*)d_in[17];
  const float* lnf_w = (const float*)d_in[18];
  const float* lnf_b = (const float*)d_in[19];
  float* out = (float*)d_out;

  const long long T = 16384, D = 1024, F = 4096, S = 2048;
  const size_t MB = 1ull << 20;
  char* base = (char*)d_ws;

  if (ws_size < 224 * MB) {
    zero_out_k<<<dim3((out_size + 255) / 256), 256, 0, stream>>>(out, out_size);
    diag_k<<<dim3(1), 1, 0, stream>>>(out, (float)ws_size);
    return;
  }

  // ---- 224 MB phase-multiplexed layout ----
  u16* rA16 = (u16*)base;                  // 0..32MB   residual bf16
  u16* rB   = (u16*)(base + 32 * MB);      // 32..64MB  normalized / Vt
  u16* QKV  = (u16*)(base + 64 * MB);      // 64..160MB [16384][3072] / CB
  u16* SC   = (u16*)(base + 160 * MB);     // 160..224MB W3+qkvb -> scores -> PW
  u16* W3   = SC;                          // [3072][1024] bf16 (6MB)
  float* qkvb = (float*)(base + 166 * MB); // 12KB
  u16* PW  = SC;                           // pw bf16 (2MB), post-PV
  u16* CB  = QKV;                          // [16384][4096] bf16, FFN
  u16* F1  = (u16*)(base + 192 * MB);      // [4096][1024] (8MB)
  u16* F2  = (u16*)(base + 200 * MB);      // [1024][4096] (8MB)

  auto cvt = [&](const float* src, u16* dst, long long n) {
    int n4 = (int)(n / 4);
    f32_to_bf16_v4<<<dim3((n4 + 255) / 256), dim3(256), 0, stream>>>(src, dst, n4);
  };
  auto gemm = [&](const u16* A, const u16* B, u16* C, const float* bias,
                  const u16* res, long long M, long long N, long long K,
                  long long lda, long long ldb, long long ldc, float alpha,
                  int flags, long long sA, long long sB, long long sC,
                  int gx, int gz) {
    gemm256<<<dim3(gx, 1, gz), dim3(512), 0, stream>>>(
        A, B, C, bias, res, (int)M, (int)N, (int)K, (int)lda, (int)ldb,
        (int)ldc, alpha, flags, sA, sB, sC);
  };

  // phase 0: fused QKV weights + biases into SC region (dead until scores)
  cvt(qw, W3, D * D);
  cvt(kw, W3 + 1024 * 1024, D * D);
  cvt(vw, W3 + 2 * 1024 * 1024, D * D);
  hipMemcpyAsync(qkvb, qb, D * 4, hipMemcpyDeviceToDevice, stream);
  hipMemcpyAsync(qkvb + 1024, kb, D * 4, hipMemcpyDeviceToDevice, stream);
  hipMemcpyAsync(qkvb + 2048, vb, D * 4, hipMemcpyDeviceToDevice, stream);

  embed_ln1<<<dim3(T / 4), 256, 0, stream>>>(x, tok_emb, ln1_w, ln1_b, rA16, rB);

  // fused QKV projection: [16384][3072]
  gemm(rB, W3, QKV, qkvb, nullptr, T, 3072, D, D, D, 3072, 1.f, FLAG_BIAS,
       0, 0, 0, 768, 1);

  // scores = (Q K^T)/32, flat causal triangle (36 blocks x 8 batches)
  gemm(QKV, QKV + 1024, SC, nullptr, nullptr, S, S, D, 3072, 3072, 2048,
       0.03125f, FLAG_TRI, S * 3072, S * 3072, S * S, 288, 1);

  // V^T per batch into rB (rB dead after QKV gemm)
  transpose_v<<<dim3(512, 1, 8), 256, 0, stream>>>(QKV + 2048, rB, 3072);

  softmax_causal<<<dim3(T / 4), 256, 0, stream>>>(SC);

  // attn out = P @ V^T, causal K-limit, into dead Q columns
  gemm(SC, rB, QKV, nullptr, nullptr, S, D, S, S, S, 3072, 1.f, FLAG_CK,
       S * S, D * S, S * 3072, 32, 8);

  // out-proj + residual (scores dead -> PW at SC)
  cvt(pw, PW, D * D);
  gemm(QKV, PW, rA16, pb, rA16, T, D, D, 3072, D, D, 1.f, FLAG_BIAS | FLAG_RES,
       0, 0, 0, 256, 1);

  ln_rows<<<dim3(T / 4), 256, 0, stream>>>(rA16, ln2_w, ln2_b, rB);

  // FFN single-pass: CB [16384][4096] over dead QKV region
  cvt(f1w, F1, F * D);
  cvt(f2w, F2, D * F);
  gemm(rB, F1, CB, f1b, nullptr, T, F, D, D, D, F, 1.f, FLAG_BIAS | FLAG_GELU,
       0, 0, 0, 1024, 1);
  gemm(CB, F2, rA16, f2b, rA16, T, D, F, F, F, D, 1.f, FLAG_BIAS | FLAG_RES,
       0, 0, 0, 256, 1);

  lnf_logits<<<dim3(512), 256, 0, stream>>>(rA16, lnf_w, lnf_b, tok_emb, out);
}

// Round 16
// 792.562 us; speedup vs baseline: 1.1939x; 1.0174x over previous
//
#include <hip/hip_runtime.h>
#include <math.h>

typedef unsigned short u16;
typedef __attribute__((ext_vector_type(8))) short short8;
typedef __attribute__((ext_vector_type(8))) __bf16 bf16x8;
typedef __attribute__((ext_vector_type(4))) float f32x4;

#define FLAG_BIAS   1
#define FLAG_RES    2
#define FLAG_GELU   4
#define FLAG_TRI    8
#define FLAG_CK     16

__device__ __forceinline__ u16 f2bf(float f) {
  unsigned u = __builtin_bit_cast(unsigned, f);
  unsigned r = u + 0x7fffu + ((u >> 16) & 1u);   // RNE
  return (u16)(r >> 16);
}
__device__ __forceinline__ float bf2f(u16 u) {
  return __builtin_bit_cast(float, (unsigned)u << 16);
}
__device__ __forceinline__ float wred_sum(float v) {
#pragma unroll
  for (int m = 32; m; m >>= 1) v += __shfl_xor(v, m, 64);
  return v;
}
__device__ __forceinline__ float wred_max(float v) {
#pragma unroll
  for (int m = 32; m; m >>= 1) v = fmaxf(v, __shfl_xor(v, m, 64));
  return v;
}
// tanh-form GELU: max dev ~3e-3, below bf16 rounding of activations
__device__ __forceinline__ float gelu_fast(float x) {
  float y = 0.7978845608f * x * (1.f + 0.044715f * x * x);
  float e = __expf(2.f * y);
  float th = 1.f - 2.f / (e + 1.f);
  return 0.5f * x * (1.f + th);
}
__device__ __forceinline__ f32x4 mfma16(short8 a, short8 b, f32x4 c) {
  return __builtin_amdgcn_mfma_f32_16x16x32_bf16(
      __builtin_bit_cast(bf16x8, a), __builtin_bit_cast(bf16x8, b), c, 0, 0, 0);
}

#define GLOAD_LDS16(gptr, lptr)                                              \
  __builtin_amdgcn_global_load_lds(                                          \
      (const __attribute__((address_space(1))) void*)(gptr),                 \
      (__attribute__((address_space(3))) void*)(lptr), 16, 0, 0)

// ---------------------------------------------------------------------------
// 256x256 bt-GEMM, BK=64, 512 thr (8 waves 2Mx4N, wave-tile 128x64),
// double-buffered LDS [2][256*64] per operand = 128KB. MINIMAL-SYNC (r11):
// one vmcnt(0) + one raw s_barrier per K-tile, no lgkmcnt/sched_barrier
// pins (m141). Conflict-free chunk-XOR swizzle with HOISTED lane-constant
// keys (rr&7 == frow&7 since all fragment-row offsets are 0 mod 8).
// 4x4 SUPERTILE ordering (r15 WIN: FETCH 270->98MB): 16 consecutive swz
// share a 4MB A+B slab (one XCD L2); supertiles walk st_m fast.
// T5 setprio around MFMA clusters: minimal-sync free-runs waves between
// barriers (role diversity), the regime where setprio pays (m191/m218b);
// lockstep null (m190) does not apply here.
// NOTE: no __launch_bounds__ min-waves (r8 spill disaster).
// C[M,N] = epi(alpha * A[M,K] @ B[N,K]^T)
// ---------------------------------------------------------------------------
__global__ __launch_bounds__(512) void gemm256(
    const u16* __restrict__ Aptr, const u16* __restrict__ Bptr,
    u16* __restrict__ Cptr, const float* __restrict__ bias,
    const u16* __restrict__ resp,
    int M, int N, int K, int lda, int ldb, int ldc, float alpha, int flags,
    long long sA, long long sB, long long sC) {
  const int nwg = gridDim.x;
  const int cpx = nwg >> 3;                 // all grids %8 == 0
  const int bid = blockIdx.x;
  const int swz = (bid & 7) * cpx + (bid >> 3);
  int bm, bn, z;
  if (flags & FLAG_TRI) {                   // flat lower triangle (8 rows) + z
    z = swz / 36;
    int tq = swz - z * 36;
    bm = (int)((sqrtf(8.f * tq + 1.f) - 1.f) * 0.5f);
    while ((bm + 1) * (bm + 2) / 2 <= tq) ++bm;
    while (bm * (bm + 1) / 2 > tq) --bm;
    bn = tq - bm * (bm + 1) / 2;
  } else {
    // 4x4 supertile decode: 16 consecutive swz share A-slab+B-slab (4MB);
    // supertiles column-major (st_m fast) -> B-slab L2-resident per XCD.
    z = blockIdx.z;
    const int nbm = M >> 8;                 // %4 == 0 for all our shapes
    const int nsm = nbm >> 2;
    const int s = swz >> 4, lcl = swz & 15;
    const int stm = s % nsm, stn = s / nsm;
    bm = stm * 4 + (lcl >> 2);
    bn = stn * 4 + (lcl & 3);
  }
  const int gm0 = bm << 8, gn0 = bn << 8;
  const int kend = (flags & FLAG_CK) ? min(K, gm0 + 256) : K;
  const int NT = kend >> 6;                 // K-tiles of 64

  __shared__ __align__(16) u16 As[2][256 * 64];
  __shared__ __align__(16) u16 Bs[2][256 * 64];

  const int t = threadIdx.x;
  const int l = t & 63;
  const int w = t >> 6;                     // wave 0..7
  const int wr = w >> 2, wc = w & 3;        // 2M x 4N; wave-tile 128x64
  const int frow = l & 15;
  const int g4 = l >> 4;                    // k-quarter 0..3
  // hoisted lane-constant swizzle byte-element offsets (rr&7 == frow&7)
  const int xk0 = ((g4 ^ (frow & 7)) << 3);
  const int xk1 = (((4 + g4) ^ (frow & 7)) << 3);

  // staging: op j covers rows j*64 + (t>>3); 8 chunks of 16B per 128B row;
  // source chunk pre-swizzled by row&7 (read side XORs the same key)
  const int srow = t >> 3;                  // 0..63
  const int sch = (t & 7) ^ (srow & 7);
  const u16* Ag = Aptr + (size_t)z * sA + (size_t)(gm0 + srow) * lda + sch * 8;
  const u16* Bg = Bptr + (size_t)z * sB + (size_t)(gn0 + srow) * ldb + sch * 8;

  auto SA = [&](int buf, int j, int kt) {
    GLOAD_LDS16(Ag + (size_t)j * 64 * lda + kt, &As[buf][j * 4096 + w * 512]);
  };
  auto SB = [&](int buf, int j, int kt) {
    GLOAD_LDS16(Bg + (size_t)j * 64 * ldb + kt, &Bs[buf][j * 4096 + w * 512]);
  };

  f32x4 acc[8][4] = {};

  // prologue: tile 0 fully staged
#pragma unroll
  for (int j = 0; j < 4; ++j) { SA(0, j, 0); SB(0, j, 0); }
  asm volatile("s_waitcnt vmcnt(0)" ::: "memory");
  __builtin_amdgcn_s_barrier();
  asm volatile("" ::: "memory");

  for (int tt = 0; tt < NT; ++tt) {
    const int buf = tt & 1;
    const int ktn = (tt + 1) << 6;
    const bool pre = (tt + 1) < NT;
    short8 af[8], bf[4];

    // ===== kk = 0 =====
#pragma unroll
    for (int m = 0; m < 8; ++m) {
      int rr = wr * 128 + m * 16 + frow;
      af[m] = *(const short8*)&As[buf][rr * 64 + xk0];
    }
#pragma unroll
    for (int n = 0; n < 4; ++n) {
      int rr = wc * 64 + n * 16 + frow;
      bf[n] = *(const short8*)&Bs[buf][rr * 64 + xk0];
    }
    if (pre) {
#pragma unroll
      for (int j = 0; j < 4; ++j) SA(buf ^ 1, j, ktn);
    }
    __builtin_amdgcn_s_setprio(1);
#pragma unroll
    for (int m = 0; m < 8; ++m)
#pragma unroll
      for (int n = 0; n < 4; ++n)
        acc[m][n] = mfma16(af[m], bf[n], acc[m][n]);
    __builtin_amdgcn_s_setprio(0);

    // ===== kk = 32 =====
#pragma unroll
    for (int m = 0; m < 8; ++m) {
      int rr = wr * 128 + m * 16 + frow;
      af[m] = *(const short8*)&As[buf][rr * 64 + xk1];
    }
#pragma unroll
    for (int n = 0; n < 4; ++n) {
      int rr = wc * 64 + n * 16 + frow;
      bf[n] = *(const short8*)&Bs[buf][rr * 64 + xk1];
    }
    if (pre) {
#pragma unroll
      for (int j = 0; j < 4; ++j) SB(buf ^ 1, j, ktn);
    }
    __builtin_amdgcn_s_setprio(1);
#pragma unroll
    for (int m = 0; m < 8; ++m)
#pragma unroll
      for (int n = 0; n < 4; ++n)
        acc[m][n] = mfma16(af[m], bf[n], acc[m][n]);
    __builtin_amdgcn_s_setprio(0);

    // single sync point per K-tile: own stages drained, then barrier
    asm volatile("s_waitcnt vmcnt(0)" ::: "memory");
    __builtin_amdgcn_s_barrier();
    asm volatile("" ::: "memory");
  }

  u16* Cb = Cptr + (size_t)z * sC;
  const bool hasB = flags & FLAG_BIAS, hasR = flags & FLAG_RES;
  const bool doG = flags & FLAG_GELU;
#pragma unroll
  for (int m = 0; m < 8; ++m) {
#pragma unroll
    for (int n = 0; n < 4; ++n) {
      int row0 = gm0 + wr * 128 + m * 16 + ((l >> 4) << 2);
      int col = gn0 + wc * 64 + n * 16 + frow;
      float bv = hasB ? bias[col] : 0.0f;
#pragma unroll
      for (int i = 0; i < 4; ++i) {
        float v = acc[m][n][i] * alpha + bv;
        if (doG) v = gelu_fast(v);
        size_t idx = (size_t)(row0 + i) * ldc + col;
        if (hasR) v += bf2f(resp[idx]);
        Cb[idx] = f2bf(v);
      }
    }
  }
}

// ---------------------------------------------------------------------------
__global__ __launch_bounds__(256) void f32_to_bf16_v4(const float* __restrict__ in,
                                                      u16* __restrict__ out, int n4) {
  int i = blockIdx.x * 256 + threadIdx.x;
  if (i < n4) {
    float4 v = ((const float4*)in)[i];
    ushort4 o;
    o.x = f2bf(v.x); o.y = f2bf(v.y); o.z = f2bf(v.z); o.w = f2bf(v.w);
    ((ushort4*)out)[i] = o;
  }
}

// embed gather + LN1
__global__ __launch_bounds__(256) void embed_ln1(
    const int* __restrict__ x, const float* __restrict__ emb,
    const float* __restrict__ w, const float* __restrict__ b,
    u16* __restrict__ h16, u16* __restrict__ hn) {
  int row = blockIdx.x * 4 + (threadIdx.x >> 6);
  int lane = threadIdx.x & 63;
  int tok = x[row];
  const float* e = emb + (size_t)tok * 1024;
  float v[16];
  float s = 0.f, q = 0.f;
#pragma unroll
  for (int i = 0; i < 16; ++i) { v[i] = e[lane + i * 64]; s += v[i]; q += v[i] * v[i]; }
  s = wred_sum(s); q = wred_sum(q);
  float mu = s * (1.0f / 1024.0f);
  float rstd = rsqrtf(q * (1.0f / 1024.0f) - mu * mu + 1e-5f);
  u16* hr = h16 + (size_t)row * 1024;
  u16* hnr = hn + (size_t)row * 1024;
#pragma unroll
  for (int i = 0; i < 16; ++i) {
    int d = lane + i * 64;
    hr[d] = f2bf(v[i]);
    hnr[d] = f2bf((v[i] - mu) * rstd * w[d] + b[d]);
  }
}

__global__ __launch_bounds__(256) void ln_rows(
    const u16* __restrict__ in, const float* __restrict__ w,
    const float* __restrict__ b, u16* __restrict__ out) {
  int row = blockIdx.x * 4 + (threadIdx.x >> 6);
  int lane = threadIdx.x & 63;
  const short8* ir = (const short8*)(in + (size_t)row * 1024);
  short8 c0 = ir[lane], c1 = ir[lane + 64];
  float v[16];
  float s = 0.f, q = 0.f;
#pragma unroll
  for (int j = 0; j < 8; ++j) {
    v[j] = bf2f((u16)c0[j]); v[8 + j] = bf2f((u16)c1[j]);
  }
#pragma unroll
  for (int j = 0; j < 16; ++j) { s += v[j]; q += v[j] * v[j]; }
  s = wred_sum(s); q = wred_sum(q);
  float mu = s * (1.0f / 1024.0f);
  float rstd = rsqrtf(q * (1.0f / 1024.0f) - mu * mu + 1e-5f);
  short8 o0, o1;
#pragma unroll
  for (int j = 0; j < 8; ++j) {
    int d0 = lane * 8 + j, d1 = 512 + lane * 8 + j;
    o0[j] = (short)f2bf((v[j] - mu) * rstd * w[d0] + b[d0]);
    o1[j] = (short)f2bf((v[8 + j] - mu) * rstd * w[d1] + b[d1]);
  }
  short8* orow = (short8*)(out + (size_t)row * 1024);
  orow[lane] = o0; orow[lane + 64] = o1;
}

// in-place causal softmax, column-trimmed to ceil512(i+1)
__global__ __launch_bounds__(256) void softmax_causal(u16* att) {
  int r = blockIdx.x * 4 + (threadIdx.x >> 6);
  int lane = threadIdx.x & 63;
  int i = r & 2047;
  int n = i + 1;
  int ng = (i >> 9) + 1;
  short8* pv = (short8*)(att + (size_t)r * 2048);
  float v[32];
  float m = -1e30f;
#pragma unroll
  for (int g = 0; g < 4; ++g) {
    if (g < ng) {
      short8 c = pv[g * 64 + lane];
#pragma unroll
      for (int j = 0; j < 8; ++j) {
        int idx = g * 512 + lane * 8 + j;
        float f = (idx < n) ? bf2f((u16)c[j]) : -1e30f;
        v[g * 8 + j] = f;
        m = fmaxf(m, f);
      }
    }
  }
  m = wred_max(m);
  float s = 0.f;
#pragma unroll
  for (int g = 0; g < 4; ++g) {
    if (g < ng) {
#pragma unroll
      for (int j = 0; j < 8; ++j) {
        int idx = g * 512 + lane * 8 + j;
        float e = (idx < n) ? __expf(v[g * 8 + j] - m) : 0.f;
        v[g * 8 + j] = e; s += e;
      }
    }
  }
  s = wred_sum(s);
  float inv = 1.0f / s;
#pragma unroll
  for (int g = 0; g < 4; ++g) {
    if (g < ng) {
      short8 o;
#pragma unroll
      for (int j = 0; j < 8; ++j) o[j] = (short)f2bf(v[g * 8 + j] * inv);
      pv[g * 64 + lane] = o;
    }
  }
}

// V (strided ldv) [z][2048][*] -> Vt [z][1024][2048]
__global__ __launch_bounds__(256) void transpose_v(const u16* __restrict__ V,
                                                   u16* __restrict__ Vt, int ldv) {
  int z = blockIdx.z;
  const u16* src = V + (size_t)z * 2048 * ldv;
  u16* dst = Vt + (size_t)z * 1024 * 2048;
  int j0 = (blockIdx.x >> 4) << 6;
  int d0 = (blockIdx.x & 15) << 6;
  __shared__ u16 tile[64][65];
  int c = threadIdx.x & 15;
  int rr = threadIdx.x >> 4;
#pragma unroll
  for (int q = 0; q < 4; ++q) {
    int row = rr + q * 16;
    ushort4 val = *(const ushort4*)(src + (size_t)(j0 + row) * ldv + d0 + c * 4);
    tile[row][c * 4 + 0] = val.x; tile[row][c * 4 + 1] = val.y;
    tile[row][c * 4 + 2] = val.z; tile[row][c * 4 + 3] = val.w;
  }
  __syncthreads();
#pragma unroll
  for (int q = 0; q < 4; ++q) {
    int drow = rr + q * 16;
    ushort4 o;
    o.x = tile[c * 4 + 0][drow]; o.y = tile[c * 4 + 1][drow];
    o.z = tile[c * 4 + 2][drow]; o.w = tile[c * 4 + 3][drow];
    *(ushort4*)(dst + (size_t)(d0 + drow) * 2048 + j0 + c * 4) = o;
  }
}

// final LN + logits (N=14), emb staged in padded LDS
__global__ __launch_bounds__(256) void lnf_logits(
    const u16* __restrict__ h, const float* __restrict__ w,
    const float* __restrict__ b, const float* __restrict__ emb,
    float* __restrict__ out) {
  __shared__ float el[14 * 1056];
  int t = threadIdx.x;
  for (int f = t * 4; f < 14 * 1024; f += 1024) {
    float4 e = *(const float4*)(emb + f);
    int v = f >> 10, d = f & 1023;
    float* dst = el + v * 1056 + d + (d >> 5);
    dst[0] = e.x; dst[1] = e.y; dst[2] = e.z; dst[3] = e.w;
  }
  __syncthreads();
  int lane = t & 63, wid = t >> 6;
  float w0[8], w1[8], b0[8], b1[8];
#pragma unroll
  for (int j = 0; j < 8; ++j) {
    int d0 = lane * 8 + j, d1 = 512 + lane * 8 + j;
    w0[j] = w[d0]; b0[j] = b[d0];
    w1[j] = w[d1]; b1[j] = b[d1];
  }
  const float* e0 = el + lane * 8 + (lane >> 2);
  const float* e1 = el + 528 + lane * 8 + (lane >> 2);
  for (int rr = 0; rr < 8; ++rr) {
    int row = blockIdx.x * 32 + wid * 8 + rr;
    const short8* hr = (const short8*)(h + (size_t)row * 1024);
    short8 c0 = hr[lane], c1 = hr[lane + 64];
    float v0[8], v1[8];
    float s = 0.f, q = 0.f;
#pragma unroll
    for (int j = 0; j < 8; ++j) {
      v0[j] = bf2f((u16)c0[j]); v1[j] = bf2f((u16)c1[j]);
      s += v0[j] + v1[j];
      q += v0[j] * v0[j] + v1[j] * v1[j];
    }
    s = wred_sum(s); q = wred_sum(q);
    float mu = s * (1.0f / 1024.0f);
    float rstd = rsqrtf(q * (1.0f / 1024.0f) - mu * mu + 1e-5f);
    float h0[8], h1[8];
#pragma unroll
    for (int j = 0; j < 8; ++j) {
      h0[j] = (v0[j] - mu) * rstd * w0[j] + b0[j];
      h1[j] = (v1[j] - mu) * rstd * w1[j] + b1[j];
    }
    float p[14];
#pragma unroll
    for (int v = 0; v < 14; ++v) {
      const float* ev0 = e0 + v * 1056;
      const float* ev1 = e1 + v * 1056;
      float a = 0.f;
#pragma unroll
      for (int j = 0; j < 8; ++j) a += h0[j] * ev0[j] + h1[j] * ev1[j];
      p[v] = a;
    }
#pragma unroll
    for (int m = 32; m; m >>= 1)
#pragma unroll
      for (int v = 0; v < 14; ++v) p[v] += __shfl_xor(p[v], m, 64);
    if (lane == 0) {
      float* orow = out + (size_t)row * 14;
#pragma unroll
      for (int v = 0; v < 14; ++v) orow[v] = p[v];
    }
  }
}

__global__ void zero_out_k(float* o, int n) {
  int i = blockIdx.x * 256 + threadIdx.x;
  if (i < n) o[i] = 0.f;
}
__global__ void diag_k(float* o, float v) { if (threadIdx.x == 0) o[0] = v; }

// ---------------------------------------------------------------------------
extern "C" void kernel_launch(void* const* d_in, const int* in_sizes, int n_in,
                              void* d_out, int out_size, void* d_ws, size_t ws_size,
                              hipStream_t stream) {
  const int* x = (const int*)d_in[0];
  const float* tok_emb = (const float*)d_in[1];
  const float* ln1_w = (const float*)d_in[2];
  const float* ln1_b = (const float*)d_in[3];
  const float* qw = (const float*)d_in[4];
  const float* qb = (const float*)d_in[5];
  const float* kw = (const float*)d_in[6];
  const float* kb = (const float*)d_in[7];
  const float* vw = (const float*)d_in[8];
  const float* vb = (const float*)d_in[9];
  const float* pw = (const float*)d_in[10];
  const float* pb = (const float*)d_in[11];
  const float* ln2_w = (const float*)d_in[12];
  const float* ln2_b = (const float*)d_in[13];
  const float* f1w = (const float*)d_in[14];
  const float* f1b = (const float*)d_in[15];
  const float* f2w = (const float*)d_in[16];
  const float* f2b = (const float*)d_in[17];
  const float* lnf_w = (const float*)d_in[18];
  const float* lnf_b = (const float*)d_in[19];
  float* out = (float*)d_out;

  const long long T = 16384, D = 1024, F = 4096, S = 2048;
  const size_t MB = 1ull << 20;
  char* base = (char*)d_ws;

  if (ws_size < 224 * MB) {
    zero_out_k<<<dim3((out_size + 255) / 256), 256, 0, stream>>>(out, out_size);
    diag_k<<<dim3(1), 1, 0, stream>>>(out, (float)ws_size);
    return;
  }

  // ---- 224 MB phase-multiplexed layout ----
  u16* rA16 = (u16*)base;                  // 0..32MB   residual bf16
  u16* rB   = (u16*)(base + 32 * MB);      // 32..64MB  normalized / Vt
  u16* QKV  = (u16*)(base + 64 * MB);      // 64..160MB [16384][3072] / CB
  u16* SC   = (u16*)(base + 160 * MB);     // 160..224MB W3+qkvb -> scores -> PW
  u16* W3   = SC;                          // [3072][1024] bf16 (6MB)
  float* qkvb = (float*)(base + 166 * MB); // 12KB
  u16* PW  = SC;                           // pw bf16 (2MB), post-PV
  u16* CB  = QKV;                          // [16384][4096] bf16, FFN
  u16* F1  = (u16*)(base + 192 * MB);      // [4096][1024] (8MB)
  u16* F2  = (u16*)(base + 200 * MB);      // [1024][4096] (8MB)

  auto cvt = [&](const float* src, u16* dst, long long n) {
    int n4 = (int)(n / 4);
    f32_to_bf16_v4<<<dim3((n4 + 255) / 256), dim3(256), 0, stream>>>(src, dst, n4);
  };
  auto gemm = [&](const u16* A, const u16* B, u16* C, const float* bias,
                  const u16* res, long long M, long long N, long long K,
                  long long lda, long long ldb, long long ldc, float alpha,
                  int flags, long long sA, long long sB, long long sC,
                  int gx, int gz) {
    gemm256<<<dim3(gx, 1, gz), dim3(512), 0, stream>>>(
        A, B, C, bias, res, (int)M, (int)N, (int)K, (int)lda, (int)ldb,
        (int)ldc, alpha, flags, sA, sB, sC);
  };

  // phase 0: fused QKV weights + biases into SC region (dead until scores)
  cvt(qw, W3, D * D);
  cvt(kw, W3 + 1024 * 1024, D * D);
  cvt(vw, W3 + 2 * 1024 * 1024, D * D);
  hipMemcpyAsync(qkvb, qb, D * 4, hipMemcpyDeviceToDevice, stream);
  hipMemcpyAsync(qkvb + 1024, kb, D * 4, hipMemcpyDeviceToDevice, stream);
  hipMemcpyAsync(qkvb + 2048, vb, D * 4, hipMemcpyDeviceToDevice, stream);

  embed_ln1<<<dim3(T / 4), 256, 0, stream>>>(x, tok_emb, ln1_w, ln1_b, rA16, rB);

  // fused QKV projection: [16384][3072]
  gemm(rB, W3, QKV, qkvb, nullptr, T, 3072, D, D, D, 3072, 1.f, FLAG_BIAS,
       0, 0, 0, 768, 1);

  // scores = (Q K^T)/32, flat causal triangle (36 blocks x 8 batches)
  gemm(QKV, QKV + 1024, SC, nullptr, nullptr, S, S, D, 3072, 3072, 2048,
       0.03125f, FLAG_TRI, S * 3072, S * 3072, S * S, 288, 1);

  // V^T per batch into rB (rB dead after QKV gemm)
  transpose_v<<<dim3(512, 1, 8), 256, 0, stream>>>(QKV + 2048, rB, 3072);

  softmax_causal<<<dim3(T / 4), 256, 0, stream>>>(SC);

  // attn out = P @ V^T, causal K-limit, into dead Q columns
  gemm(SC, rB, QKV, nullptr, nullptr, S, D, S, S, S, 3072, 1.f, FLAG_CK,
       S * S, D * S, S * 3072, 32, 8);

  // out-proj + residual (scores dead -> PW at SC)
  cvt(pw, PW, D * D);
  gemm(QKV, PW, rA16, pb, rA16, T, D, D, 3072, D, D, 1.f, FLAG_BIAS | FLAG_RES,
       0, 0, 0, 256, 1);

  ln_rows<<<dim3(T / 4), 256, 0, stream>>>(rA16, ln2_w, ln2_b, rB);

  // FFN single-pass: CB [16384][4096] over dead QKV region
  cvt(f1w, F1, F * D);
  cvt(f2w, F2, D * F);
  gemm(rB, F1, CB, f1b, nullptr, T, F, D, D, D, F, 1.f, FLAG_BIAS | FLAG_GELU,
       0, 0, 0, 1024, 1);
  gemm(CB, F2, rA16, f2b, rA16, T, D, F, F, F, D, 1.f, FLAG_BIAS | FLAG_RES,
       0, 0, 0, 256, 1);

  lnf_logits<<<dim3(512), 256, 0, stream>>>(rA16, lnf_w, lnf_b, tok_emb, out);
}

// Round 17
// 746.504 us; speedup vs baseline: 1.2676x; 1.0617x over previous
//
#include <hip/hip_runtime.h>
#include <math.h>

typedef unsigned short u16;
typedef __attribute__((ext_vector_type(8))) short short8;
typedef __attribute__((ext_vector_type(8))) __bf16 bf16x8;
typedef __attribute__((ext_vector_type(4))) float f32x4;

#define FLAG_BIAS   1
#define FLAG_RES    2
#define FLAG_GELU   4
#define FLAG_TRI    8
#define FLAG_CK     16

__device__ __forceinline__ u16 f2bf(float f) {
  unsigned u = __builtin_bit_cast(unsigned, f);
  unsigned r = u + 0x7fffu + ((u >> 16) & 1u);   // RNE
  return (u16)(r >> 16);
}
__device__ __forceinline__ float bf2f(u16 u) {
  return __builtin_bit_cast(float, (unsigned)u << 16);
}
__device__ __forceinline__ float wred_sum(float v) {
#pragma unroll
  for (int m = 32; m; m >>= 1) v += __shfl_xor(v, m, 64);
  return v;
}
__device__ __forceinline__ float wred_max(float v) {
#pragma unroll
  for (int m = 32; m; m >>= 1) v = fmaxf(v, __shfl_xor(v, m, 64));
  return v;
}
// tanh-form GELU: max dev ~3e-3, below bf16 rounding of activations
__device__ __forceinline__ float gelu_fast(float x) {
  float y = 0.7978845608f * x * (1.f + 0.044715f * x * x);
  float e = __expf(2.f * y);
  float th = 1.f - 2.f / (e + 1.f);
  return 0.5f * x * (1.f + th);
}
__device__ __forceinline__ f32x4 mfma16(short8 a, short8 b, f32x4 c) {
  return __builtin_amdgcn_mfma_f32_16x16x32_bf16(
      __builtin_bit_cast(bf16x8, a), __builtin_bit_cast(bf16x8, b), c, 0, 0, 0);
}

#define GLOAD_LDS16(gptr, lptr)                                              \
  __builtin_amdgcn_global_load_lds(                                          \
      (const __attribute__((address_space(1))) void*)(gptr),                 \
      (__attribute__((address_space(3))) void*)(lptr), 16, 0, 0)

// ---------------------------------------------------------------------------
// 128x128 bt-GEMM (m97 geometry — the measured-best tile for simple
// 2-barrier loops: 912 TF vs 792 at 256², m103/m112): BK=64, 256 thr
// (4 waves 2x2, wave-tile 64x64, acc[4][4]=64 AGPR + ~70 VGPR -> 3
// waves/SIMD -> 3 BLOCKS/CU; cross-block overlap hides barrier drain,
// m114). Single-buffered 32KB LDS, 2 __syncthreads per K-tile.
// + r15/r16 verified add-ons: 4x4 SUPERTILE ordering (1MB A-slab + 1MB
// B-slab L2-resident; fixes r14's 550MB FETCH), conflict-free chunk-XOR
// swizzle (fixes r14's 50M bank conflicts; rr&7 == frow&7 here too),
// setprio around MFMA clusters (+14us in r16).
// C[M,N] = epi(alpha * A[M,K] @ B[N,K]^T)
// ---------------------------------------------------------------------------
__global__ __launch_bounds__(256, 3) void gemm128(
    const u16* __restrict__ Aptr, const u16* __restrict__ Bptr,
    u16* __restrict__ Cptr, const float* __restrict__ bias,
    const u16* __restrict__ resp,
    int M, int N, int K, int lda, int ldb, int ldc, float alpha, int flags,
    long long sA, long long sB, long long sC) {
  const int nwg = gridDim.x;
  const int cpx = nwg >> 3;                 // all grids %8 == 0
  const int bid = blockIdx.x;
  const int swz = (bid & 7) * cpx + (bid >> 3);
  int bm, bn, z;
  if (flags & FLAG_TRI) {                   // flat lower triangle, 16 rows
    z = swz / 136;
    int tq = swz - z * 136;
    bm = (int)((sqrtf(8.f * tq + 1.f) - 1.f) * 0.5f);
    while ((bm + 1) * (bm + 2) / 2 <= tq) ++bm;
    while (bm * (bm + 1) / 2 > tq) --bm;
    bn = tq - bm * (bm + 1) / 2;
  } else {
    // 4x4 supertile: 16 consecutive swz share 1MB A-slab + 1MB B-slab;
    // supertiles column-major (st_m fast) -> B-slab L2-resident per XCD.
    z = blockIdx.z;
    const int nbm = M >> 7;                 // %4 == 0 for all our shapes
    const int nsm = nbm >> 2;
    const int s = swz >> 4, lcl = swz & 15;
    const int stm = s % nsm, stn = s / nsm;
    bm = stm * 4 + (lcl >> 2);
    bn = stn * 4 + (lcl & 3);
  }
  const int gm0 = bm << 7, gn0 = bn << 7;
  const int kend = (flags & FLAG_CK) ? min(K, gm0 + 128) : K;

  __shared__ __align__(16) u16 As[128 * 64];
  __shared__ __align__(16) u16 Bs[128 * 64];

  const int t = threadIdx.x;
  const int l = t & 63;
  const int w = t >> 6;
  const int wr = w >> 1, wc = w & 1;        // 2x2 waves; wave-tile 64x64
  const int frow = l & 15;
  const int g4 = l >> 4;                    // k-quarter 0..3
  // hoisted lane-constant swizzle element offsets (rr&7 == frow&7)
  const int xk0 = ((g4 ^ (frow & 7)) << 3);
  const int xk1 = (((4 + g4) ^ (frow & 7)) << 3);

  // staging: per op 256 thr x 16B = 32 rows x 8 chunks; thread t -> row
  // t>>3, stored chunk t&7; SOURCE chunk pre-swizzled by row&7
  const int srow = t >> 3;                  // 0..31
  const int sch = (t & 7) ^ (srow & 7);
  const u16* Ag = Aptr + (size_t)z * sA + (size_t)(gm0 + srow) * lda + sch * 8;
  const u16* Bg = Bptr + (size_t)z * sB + (size_t)(gn0 + srow) * ldb + sch * 8;

  f32x4 acc[4][4] = {};

  for (int kt = 0; kt < kend; kt += 64) {
#pragma unroll
    for (int j = 0; j < 4; ++j) {
      GLOAD_LDS16(Ag + (size_t)j * 32 * lda + kt, &As[j * 2048 + w * 512]);
      GLOAD_LDS16(Bg + (size_t)j * 32 * ldb + kt, &Bs[j * 2048 + w * 512]);
    }
    __syncthreads();
    {
      short8 af[4], bf[4];
      // kk = 0
#pragma unroll
      for (int mt = 0; mt < 4; ++mt)
        af[mt] = *(const short8*)&As[(wr * 64 + mt * 16 + frow) * 64 + xk0];
#pragma unroll
      for (int nt = 0; nt < 4; ++nt)
        bf[nt] = *(const short8*)&Bs[(wc * 64 + nt * 16 + frow) * 64 + xk0];
      __builtin_amdgcn_s_setprio(1);
#pragma unroll
      for (int mt = 0; mt < 4; ++mt)
#pragma unroll
        for (int nt = 0; nt < 4; ++nt)
          acc[mt][nt] = mfma16(af[mt], bf[nt], acc[mt][nt]);
      __builtin_amdgcn_s_setprio(0);
      // kk = 32
#pragma unroll
      for (int mt = 0; mt < 4; ++mt)
        af[mt] = *(const short8*)&As[(wr * 64 + mt * 16 + frow) * 64 + xk1];
#pragma unroll
      for (int nt = 0; nt < 4; ++nt)
        bf[nt] = *(const short8*)&Bs[(wc * 64 + nt * 16 + frow) * 64 + xk1];
      __builtin_amdgcn_s_setprio(1);
#pragma unroll
      for (int mt = 0; mt < 4; ++mt)
#pragma unroll
        for (int nt = 0; nt < 4; ++nt)
          acc[mt][nt] = mfma16(af[mt], bf[nt], acc[mt][nt]);
      __builtin_amdgcn_s_setprio(0);
    }
    __syncthreads();
  }

  u16* Cb = Cptr + (size_t)z * sC;
  const bool hasB = flags & FLAG_BIAS, hasR = flags & FLAG_RES;
  const bool doG = flags & FLAG_GELU;
#pragma unroll
  for (int mt = 0; mt < 4; ++mt) {
#pragma unroll
    for (int nt = 0; nt < 4; ++nt) {
      int row0 = gm0 + wr * 64 + mt * 16 + ((l >> 4) << 2);
      int col = gn0 + wc * 64 + nt * 16 + frow;
      float bv = hasB ? bias[col] : 0.0f;
#pragma unroll
      for (int i = 0; i < 4; ++i) {
        float v = acc[mt][nt][i] * alpha + bv;
        if (doG) v = gelu_fast(v);
        size_t idx = (size_t)(row0 + i) * ldc + col;
        if (hasR) v += bf2f(resp[idx]);
        Cb[idx] = f2bf(v);
      }
    }
  }
}

// ---------------------------------------------------------------------------
__global__ __launch_bounds__(256) void f32_to_bf16_v4(const float* __restrict__ in,
                                                      u16* __restrict__ out, int n4) {
  int i = blockIdx.x * 256 + threadIdx.x;
  if (i < n4) {
    float4 v = ((const float4*)in)[i];
    ushort4 o;
    o.x = f2bf(v.x); o.y = f2bf(v.y); o.z = f2bf(v.z); o.w = f2bf(v.w);
    ((ushort4*)out)[i] = o;
  }
}

// embed gather + LN1
__global__ __launch_bounds__(256) void embed_ln1(
    const int* __restrict__ x, const float* __restrict__ emb,
    const float* __restrict__ w, const float* __restrict__ b,
    u16* __restrict__ h16, u16* __restrict__ hn) {
  int row = blockIdx.x * 4 + (threadIdx.x >> 6);
  int lane = threadIdx.x & 63;
  int tok = x[row];
  const float* e = emb + (size_t)tok * 1024;
  float v[16];
  float s = 0.f, q = 0.f;
#pragma unroll
  for (int i = 0; i < 16; ++i) { v[i] = e[lane + i * 64]; s += v[i]; q += v[i] * v[i]; }
  s = wred_sum(s); q = wred_sum(q);
  float mu = s * (1.0f / 1024.0f);
  float rstd = rsqrtf(q * (1.0f / 1024.0f) - mu * mu + 1e-5f);
  u16* hr = h16 + (size_t)row * 1024;
  u16* hnr = hn + (size_t)row * 1024;
#pragma unroll
  for (int i = 0; i < 16; ++i) {
    int d = lane + i * 64;
    hr[d] = f2bf(v[i]);
    hnr[d] = f2bf((v[i] - mu) * rstd * w[d] + b[d]);
  }
}

__global__ __launch_bounds__(256) void ln_rows(
    const u16* __restrict__ in, const float* __restrict__ w,
    const float* __restrict__ b, u16* __restrict__ out) {
  int row = blockIdx.x * 4 + (threadIdx.x >> 6);
  int lane = threadIdx.x & 63;
  const short8* ir = (const short8*)(in + (size_t)row * 1024);
  short8 c0 = ir[lane], c1 = ir[lane + 64];
  float v[16];
  float s = 0.f, q = 0.f;
#pragma unroll
  for (int j = 0; j < 8; ++j) {
    v[j] = bf2f((u16)c0[j]); v[8 + j] = bf2f((u16)c1[j]);
  }
#pragma unroll
  for (int j = 0; j < 16; ++j) { s += v[j]; q += v[j] * v[j]; }
  s = wred_sum(s); q = wred_sum(q);
  float mu = s * (1.0f / 1024.0f);
  float rstd = rsqrtf(q * (1.0f / 1024.0f) - mu * mu + 1e-5f);
  short8 o0, o1;
#pragma unroll
  for (int j = 0; j < 8; ++j) {
    int d0 = lane * 8 + j, d1 = 512 + lane * 8 + j;
    o0[j] = (short)f2bf((v[j] - mu) * rstd * w[d0] + b[d0]);
    o1[j] = (short)f2bf((v[8 + j] - mu) * rstd * w[d1] + b[d1]);
  }
  short8* orow = (short8*)(out + (size_t)row * 1024);
  orow[lane] = o0; orow[lane + 64] = o1;
}

// in-place causal softmax, column-trimmed to ceil512(i+1)
__global__ __launch_bounds__(256) void softmax_causal(u16* att) {
  int r = blockIdx.x * 4 + (threadIdx.x >> 6);
  int lane = threadIdx.x & 63;
  int i = r & 2047;
  int n = i + 1;
  int ng = (i >> 9) + 1;
  short8* pv = (short8*)(att + (size_t)r * 2048);
  float v[32];
  float m = -1e30f;
#pragma unroll
  for (int g = 0; g < 4; ++g) {
    if (g < ng) {
      short8 c = pv[g * 64 + lane];
#pragma unroll
      for (int j = 0; j < 8; ++j) {
        int idx = g * 512 + lane * 8 + j;
        float f = (idx < n) ? bf2f((u16)c[j]) : -1e30f;
        v[g * 8 + j] = f;
        m = fmaxf(m, f);
      }
    }
  }
  m = wred_max(m);
  float s = 0.f;
#pragma unroll
  for (int g = 0; g < 4; ++g) {
    if (g < ng) {
#pragma unroll
      for (int j = 0; j < 8; ++j) {
        int idx = g * 512 + lane * 8 + j;
        float e = (idx < n) ? __expf(v[g * 8 + j] - m) : 0.f;
        v[g * 8 + j] = e; s += e;
      }
    }
  }
  s = wred_sum(s);
  float inv = 1.0f / s;
#pragma unroll
  for (int g = 0; g < 4; ++g) {
    if (g < ng) {
      short8 o;
#pragma unroll
      for (int j = 0; j < 8; ++j) o[j] = (short)f2bf(v[g * 8 + j] * inv);
      pv[g * 64 + lane] = o;
    }
  }
}

// V (strided ldv) [z][2048][*] -> Vt [z][1024][2048]
__global__ __launch_bounds__(256) void transpose_v(const u16* __restrict__ V,
                                                   u16* __restrict__ Vt, int ldv) {
  int z = blockIdx.z;
  const u16* src = V + (size_t)z * 2048 * ldv;
  u16* dst = Vt + (size_t)z * 1024 * 2048;
  int j0 = (blockIdx.x >> 4) << 6;
  int d0 = (blockIdx.x & 15) << 6;
  __shared__ u16 tile[64][65];
  int c = threadIdx.x & 15;
  int rr = threadIdx.x >> 4;
#pragma unroll
  for (int q = 0; q < 4; ++q) {
    int row = rr + q * 16;
    ushort4 val = *(const ushort4*)(src + (size_t)(j0 + row) * ldv + d0 + c * 4);
    tile[row][c * 4 + 0] = val.x; tile[row][c * 4 + 1] = val.y;
    tile[row][c * 4 + 2] = val.z; tile[row][c * 4 + 3] = val.w;
  }
  __syncthreads();
#pragma unroll
  for (int q = 0; q < 4; ++q) {
    int drow = rr + q * 16;
    ushort4 o;
    o.x = tile[c * 4 + 0][drow]; o.y = tile[c * 4 + 1][drow];
    o.z = tile[c * 4 + 2][drow]; o.w = tile[c * 4 + 3][drow];
    *(ushort4*)(dst + (size_t)(d0 + drow) * 2048 + j0 + c * 4) = o;
  }
}

// final LN + logits (N=14), emb staged in padded LDS
__global__ __launch_bounds__(256) void lnf_logits(
    const u16* __restrict__ h, const float* __restrict__ w,
    const float* __restrict__ b, const float* __restrict__ emb,
    float* __restrict__ out) {
  __shared__ float el[14 * 1056];
  int t = threadIdx.x;
  for (int f = t * 4; f < 14 * 1024; f += 1024) {
    float4 e = *(const float4*)(emb + f);
    int v = f >> 10, d = f & 1023;
    float* dst = el + v * 1056 + d + (d >> 5);
    dst[0] = e.x; dst[1] = e.y; dst[2] = e.z; dst[3] = e.w;
  }
  __syncthreads();
  int lane = t & 63, wid = t >> 6;
  float w0[8], w1[8], b0[8], b1[8];
#pragma unroll
  for (int j = 0; j < 8; ++j) {
    int d0 = lane * 8 + j, d1 = 512 + lane * 8 + j;
    w0[j] = w[d0]; b0[j] = b[d0];
    w1[j] = w[d1]; b1[j] = b[d1];
  }
  const float* e0 = el + lane * 8 + (lane >> 2);
  const float* e1 = el + 528 + lane * 8 + (lane >> 2);
  for (int rr = 0; rr < 8; ++rr) {
    int row = blockIdx.x * 32 + wid * 8 + rr;
    const short8* hr = (const short8*)(h + (size_t)row * 1024);
    short8 c0 = hr[lane], c1 = hr[lane + 64];
    float v0[8], v1[8];
    float s = 0.f, q = 0.f;
#pragma unroll
    for (int j = 0; j < 8; ++j) {
      v0[j] = bf2f((u16)c0[j]); v1[j] = bf2f((u16)c1[j]);
      s += v0[j] + v1[j];
      q += v0[j] * v0[j] + v1[j] * v1[j];
    }
    s = wred_sum(s); q = wred_sum(q);
    float mu = s * (1.0f / 1024.0f);
    float rstd = rsqrtf(q * (1.0f / 1024.0f) - mu * mu + 1e-5f);
    float h0[8], h1[8];
#pragma unroll
    for (int j = 0; j < 8; ++j) {
      h0[j] = (v0[j] - mu) * rstd * w0[j] + b0[j];
      h1[j] = (v1[j] - mu) * rstd * w1[j] + b1[j];
    }
    float p[14];
#pragma unroll
    for (int v = 0; v < 14; ++v) {
      const float* ev0 = e0 + v * 1056;
      const float* ev1 = e1 + v * 1056;
      float a = 0.f;
#pragma unroll
      for (int j = 0; j < 8; ++j) a += h0[j] * ev0[j] + h1[j] * ev1[j];
      p[v] = a;
    }
#pragma unroll
    for (int m = 32; m; m >>= 1)
#pragma unroll
      for (int v = 0; v < 14; ++v) p[v] += __shfl_xor(p[v], m, 64);
    if (lane == 0) {
      float* orow = out + (size_t)row * 14;
#pragma unroll
      for (int v = 0; v < 14; ++v) orow[v] = p[v];
    }
  }
}

__global__ void zero_out_k(float* o, int n) {
  int i = blockIdx.x * 256 + threadIdx.x;
  if (i < n) o[i] = 0.f;
}
__global__ void diag_k(float* o, float v) { if (threadIdx.x == 0) o[0] = v; }

// ---------------------------------------------------------------------------
extern "C" void kernel_launch(void* const* d_in, const int* in_sizes, int n_in,
                              void* d_out, int out_size, void* d_ws, size_t ws_size,
                              hipStream_t stream) {
  const int* x = (const int*)d_in[0];
  const float* tok_emb = (const float*)d_in[1];
  const float* ln1_w = (const float*)d_in[2];
  const float* ln1_b = (const float*)d_in[3];
  const float* qw = (const float*)d_in[4];
  const float* qb = (const float*)d_in[5];
  const float* kw = (const float*)d_in[6];
  const float* kb = (const float*)d_in[7];
  const float* vw = (const float*)d_in[8];
  const float* vb = (const float*)d_in[9];
  const float* pw = (const float*)d_in[10];
  const float* pb = (const float*)d_in[11];
  const float* ln2_w = (const float*)d_in[12];
  const float* ln2_b = (const float*)d_in[13];
  const float* f1w = (const float*)d_in[14];
  const float* f1b = (const float*)d_in[15];
  const float* f2w = (const float*)d_in[16];
  const float* f2b = (const float*)d_in[17];
  const float* lnf_w = (const float*)d_in[18];
  const float* lnf_b = (const float*)d_in[19];
  float* out = (float*)d_out;

  const long long T = 16384, D = 1024, F = 4096, S = 2048;
  const size_t MB = 1ull << 20;
  char* base = (char*)d_ws;

  if (ws_size < 224 * MB) {
    zero_out_k<<<dim3((out_size + 255) / 256), 256, 0, stream>>>(out, out_size);
    diag_k<<<dim3(1), 1, 0, stream>>>(out, (float)ws_size);
    return;
  }

  // ---- 224 MB phase-multiplexed layout ----
  u16* rA16 = (u16*)base;                  // 0..32MB   residual bf16
  u16* rB   = (u16*)(base + 32 * MB);      // 32..64MB  normalized / Vt
  u16* QKV  = (u16*)(base + 64 * MB);      // 64..160MB [16384][3072] / CB
  u16* SC   = (u16*)(base + 160 * MB);     // 160..224MB W3+qkvb -> scores -> PW
  u16* W3   = SC;                          // [3072][1024] bf16 (6MB)
  float* qkvb = (float*)(base + 166 * MB); // 12KB
  u16* PW  = SC;                           // pw bf16 (2MB), post-PV
  u16* CB  = QKV;                          // [16384][4096] bf16, FFN
  u16* F1  = (u16*)(base + 192 * MB);      // [4096][1024] (8MB)
  u16* F2  = (u16*)(base + 200 * MB);      // [1024][4096] (8MB)

  auto cvt = [&](const float* src, u16* dst, long long n) {
    int n4 = (int)(n / 4);
    f32_to_bf16_v4<<<dim3((n4 + 255) / 256), dim3(256), 0, stream>>>(src, dst, n4);
  };
  auto gemm = [&](const u16* A, const u16* B, u16* C, const float* bias,
                  const u16* res, long long M, long long N, long long K,
                  long long lda, long long ldb, long long ldc, float alpha,
                  int flags, long long sA, long long sB, long long sC,
                  int gx, int gz) {
    gemm128<<<dim3(gx, 1, gz), dim3(256), 0, stream>>>(
        A, B, C, bias, res, (int)M, (int)N, (int)K, (int)lda, (int)ldb,
        (int)ldc, alpha, flags, sA, sB, sC);
  };

  // phase 0: fused QKV weights + biases into SC region (dead until scores)
  cvt(qw, W3, D * D);
  cvt(kw, W3 + 1024 * 1024, D * D);
  cvt(vw, W3 + 2 * 1024 * 1024, D * D);
  hipMemcpyAsync(qkvb, qb, D * 4, hipMemcpyDeviceToDevice, stream);
  hipMemcpyAsync(qkvb + 1024, kb, D * 4, hipMemcpyDeviceToDevice, stream);
  hipMemcpyAsync(qkvb + 2048, vb, D * 4, hipMemcpyDeviceToDevice, stream);

  embed_ln1<<<dim3(T / 4), 256, 0, stream>>>(x, tok_emb, ln1_w, ln1_b, rA16, rB);

  // fused QKV projection: [16384][3072]  grid 128x24
  gemm(rB, W3, QKV, qkvb, nullptr, T, 3072, D, D, D, 3072, 1.f, FLAG_BIAS,
       0, 0, 0, 3072, 1);

  // scores = (Q K^T)/32, flat causal triangle (136 blocks x 8 batches)
  gemm(QKV, QKV + 1024, SC, nullptr, nullptr, S, S, D, 3072, 3072, 2048,
       0.03125f, FLAG_TRI, S * 3072, S * 3072, S * S, 1088, 1);

  // V^T per batch into rB (rB dead after QKV gemm)
  transpose_v<<<dim3(512, 1, 8), 256, 0, stream>>>(QKV + 2048, rB, 3072);

  softmax_causal<<<dim3(T / 4), 256, 0, stream>>>(SC);

  // attn out = P @ V^T, causal K-limit, into dead Q columns (16x8 grid x8)
  gemm(SC, rB, QKV, nullptr, nullptr, S, D, S, S, S, 3072, 1.f, FLAG_CK,
       S * S, D * S, S * 3072, 128, 8);

  // out-proj + residual (scores dead -> PW at SC)
  cvt(pw, PW, D * D);
  gemm(QKV, PW, rA16, pb, rA16, T, D, D, 3072, D, D, 1.f, FLAG_BIAS | FLAG_RES,
       0, 0, 0, 1024, 1);

  ln_rows<<<dim3(T / 4), 256, 0, stream>>>(rA16, ln2_w, ln2_b, rB);

  // FFN single-pass: CB [16384][4096] over dead QKV region
  cvt(f1w, F1, F * D);
  cvt(f2w, F2, D * F);
  gemm(rB, F1, CB, f1b, nullptr, T, F, D, D, D, F, 1.f, FLAG_BIAS | FLAG_GELU,
       0, 0, 0, 4096, 1);
  gemm(CB, F2, rA16, f2b, rA16, T, D, F, F, F, D, 1.f, FLAG_BIAS | FLAG_RES,
       0, 0, 0, 1024, 1);

  lnf_logits<<<dim3(512), 256, 0, stream>>>(rA16, lnf_w, lnf_b, tok_emb, out);
}

// Round 18
// 743.975 us; speedup vs baseline: 1.2719x; 1.0034x over previous
//
#include <hip/hip_runtime.h>
#include <math.h>

typedef unsigned short u16;
typedef __attribute__((ext_vector_type(8))) short short8;
typedef __attribute__((ext_vector_type(8))) __bf16 bf16x8;
typedef __attribute__((ext_vector_type(4))) float f32x4;

#define FLAG_BIAS   1
#define FLAG_RES    2
#define FLAG_GELU   4
#define FLAG_TRI    8
#define FLAG_CK     16

// native HW convert (v_cvt_pk_bf16_f32, RNE) — compiler pairs adjacent
// converts; ~8x fewer VALU ops than the bit-twiddled RNE (r18 change)
__device__ __forceinline__ u16 f2bf(float f) {
  return __builtin_bit_cast(u16, (__bf16)f);
}
__device__ __forceinline__ float bf2f(u16 u) {
  return __builtin_bit_cast(float, (unsigned)u << 16);
}
__device__ __forceinline__ float wred_sum(float v) {
#pragma unroll
  for (int m = 32; m; m >>= 1) v += __shfl_xor(v, m, 64);
  return v;
}
__device__ __forceinline__ float wred_max(float v) {
#pragma unroll
  for (int m = 32; m; m >>= 1) v = fmaxf(v, __shfl_xor(v, m, 64));
  return v;
}
// tanh-form GELU: max dev ~3e-3, below bf16 rounding of activations
__device__ __forceinline__ float gelu_fast(float x) {
  float y = 0.7978845608f * x * (1.f + 0.044715f * x * x);
  float e = __expf(2.f * y);
  float th = 1.f - 2.f / (e + 1.f);
  return 0.5f * x * (1.f + th);
}
__device__ __forceinline__ f32x4 mfma16(short8 a, short8 b, f32x4 c) {
  return __builtin_amdgcn_mfma_f32_16x16x32_bf16(
      __builtin_bit_cast(bf16x8, a), __builtin_bit_cast(bf16x8, b), c, 0, 0, 0);
}

#define GLOAD_LDS16(gptr, lptr)                                              \
  __builtin_amdgcn_global_load_lds(                                          \
      (const __attribute__((address_space(1))) void*)(gptr),                 \
      (__attribute__((address_space(3))) void*)(lptr), 16, 0, 0)

// ---------------------------------------------------------------------------
// 128x128 bt-GEMM (m97 geometry, best measured r17: f1 MfmaUtil 38%,
// MFMA+VALU issue ~94% saturated): BK=64, 256 thr (4 waves 2x2, wave-tile
// 64x64, acc 64 AGPR + 64 VGPR -> 3 blocks/CU; cross-block overlap hides
// barrier drain, m114). Single-buffered 32KB LDS, 2 __syncthreads/K-tile.
// 4x4 SUPERTILE ordering (L2-resident slabs), conflict-free chunk-XOR
// swizzle, setprio around MFMA clusters.
// r18: native v_cvt_pk bf16 stores (epilogue VALU cut); FLAG_CK reverses
// bm so longest-K causal blocks schedule first (PV tail packing).
// C[M,N] = epi(alpha * A[M,K] @ B[N,K]^T)
// ---------------------------------------------------------------------------
__global__ __launch_bounds__(256, 3) void gemm128(
    const u16* __restrict__ Aptr, const u16* __restrict__ Bptr,
    u16* __restrict__ Cptr, const float* __restrict__ bias,
    const u16* __restrict__ resp,
    int M, int N, int K, int lda, int ldb, int ldc, float alpha, int flags,
    long long sA, long long sB, long long sC) {
  const int nwg = gridDim.x;
  const int cpx = nwg >> 3;                 // all grids %8 == 0
  const int bid = blockIdx.x;
  const int swz = (bid & 7) * cpx + (bid >> 3);
  int bm, bn, z;
  if (flags & FLAG_TRI) {                   // flat lower triangle, 16 rows
    z = swz / 136;
    int tq = swz - z * 136;
    bm = (int)((sqrtf(8.f * tq + 1.f) - 1.f) * 0.5f);
    while ((bm + 1) * (bm + 2) / 2 <= tq) ++bm;
    while (bm * (bm + 1) / 2 > tq) --bm;
    bn = tq - bm * (bm + 1) / 2;
  } else {
    // 4x4 supertile: 16 consecutive swz share 1MB A-slab + 1MB B-slab;
    // supertiles column-major (st_m fast) -> B-slab L2-resident per XCD.
    z = blockIdx.z;
    const int nbm = M >> 7;                 // %4 == 0 for all our shapes
    const int nsm = nbm >> 2;
    const int s = swz >> 4, lcl = swz & 15;
    const int stm = s % nsm, stn = s / nsm;
    bm = stm * 4 + (lcl >> 2);
    bn = stn * 4 + (lcl & 3);
    if (flags & FLAG_CK) bm = nbm - 1 - bm; // longest-K blocks first
  }
  const int gm0 = bm << 7, gn0 = bn << 7;
  const int kend = (flags & FLAG_CK) ? min(K, gm0 + 128) : K;

  __shared__ __align__(16) u16 As[128 * 64];
  __shared__ __align__(16) u16 Bs[128 * 64];

  const int t = threadIdx.x;
  const int l = t & 63;
  const int w = t >> 6;
  const int wr = w >> 1, wc = w & 1;        // 2x2 waves; wave-tile 64x64
  const int frow = l & 15;
  const int g4 = l >> 4;                    // k-quarter 0..3
  // hoisted lane-constant swizzle element offsets (rr&7 == frow&7)
  const int xk0 = ((g4 ^ (frow & 7)) << 3);
  const int xk1 = (((4 + g4) ^ (frow & 7)) << 3);

  // staging: per op 256 thr x 16B = 32 rows x 8 chunks; thread t -> row
  // t>>3, stored chunk t&7; SOURCE chunk pre-swizzled by row&7
  const int srow = t >> 3;                  // 0..31
  const int sch = (t & 7) ^ (srow & 7);
  const u16* Ag = Aptr + (size_t)z * sA + (size_t)(gm0 + srow) * lda + sch * 8;
  const u16* Bg = Bptr + (size_t)z * sB + (size_t)(gn0 + srow) * ldb + sch * 8;

  f32x4 acc[4][4] = {};

  for (int kt = 0; kt < kend; kt += 64) {
#pragma unroll
    for (int j = 0; j < 4; ++j) {
      GLOAD_LDS16(Ag + (size_t)j * 32 * lda + kt, &As[j * 2048 + w * 512]);
      GLOAD_LDS16(Bg + (size_t)j * 32 * ldb + kt, &Bs[j * 2048 + w * 512]);
    }
    __syncthreads();
    {
      short8 af[4], bf[4];
      // kk = 0
#pragma unroll
      for (int mt = 0; mt < 4; ++mt)
        af[mt] = *(const short8*)&As[(wr * 64 + mt * 16 + frow) * 64 + xk0];
#pragma unroll
      for (int nt = 0; nt < 4; ++nt)
        bf[nt] = *(const short8*)&Bs[(wc * 64 + nt * 16 + frow) * 64 + xk0];
      __builtin_amdgcn_s_setprio(1);
#pragma unroll
      for (int mt = 0; mt < 4; ++mt)
#pragma unroll
        for (int nt = 0; nt < 4; ++nt)
          acc[mt][nt] = mfma16(af[mt], bf[nt], acc[mt][nt]);
      __builtin_amdgcn_s_setprio(0);
      // kk = 32
#pragma unroll
      for (int mt = 0; mt < 4; ++mt)
        af[mt] = *(const short8*)&As[(wr * 64 + mt * 16 + frow) * 64 + xk1];
#pragma unroll
      for (int nt = 0; nt < 4; ++nt)
        bf[nt] = *(const short8*)&Bs[(wc * 64 + nt * 16 + frow) * 64 + xk1];
      __builtin_amdgcn_s_setprio(1);
#pragma unroll
      for (int mt = 0; mt < 4; ++mt)
#pragma unroll
        for (int nt = 0; nt < 4; ++nt)
          acc[mt][nt] = mfma16(af[mt], bf[nt], acc[mt][nt]);
      __builtin_amdgcn_s_setprio(0);
    }
    __syncthreads();
  }

  u16* Cb = Cptr + (size_t)z * sC;
  const bool hasB = flags & FLAG_BIAS, hasR = flags & FLAG_RES;
  const bool doG = flags & FLAG_GELU;
#pragma unroll
  for (int mt = 0; mt < 4; ++mt) {
#pragma unroll
    for (int nt = 0; nt < 4; ++nt) {
      int row0 = gm0 + wr * 64 + mt * 16 + ((l >> 4) << 2);
      int col = gn0 + wc * 64 + nt * 16 + frow;
      float bv = hasB ? bias[col] : 0.0f;
#pragma unroll
      for (int i = 0; i < 4; ++i) {
        float v = acc[mt][nt][i] * alpha + bv;
        if (doG) v = gelu_fast(v);
        size_t idx = (size_t)(row0 + i) * ldc + col;
        if (hasR) v += bf2f(resp[idx]);
        Cb[idx] = f2bf(v);
      }
    }
  }
}

// ---------------------------------------------------------------------------
__global__ __launch_bounds__(256) void f32_to_bf16_v4(const float* __restrict__ in,
                                                      u16* __restrict__ out, int n4) {
  int i = blockIdx.x * 256 + threadIdx.x;
  if (i < n4) {
    float4 v = ((const float4*)in)[i];
    ushort4 o;
    o.x = f2bf(v.x); o.y = f2bf(v.y); o.z = f2bf(v.z); o.w = f2bf(v.w);
    ((ushort4*)out)[i] = o;
  }
}

// embed gather + LN1
__global__ __launch_bounds__(256) void embed_ln1(
    const int* __restrict__ x, const float* __restrict__ emb,
    const float* __restrict__ w, const float* __restrict__ b,
    u16* __restrict__ h16, u16* __restrict__ hn) {
  int row = blockIdx.x * 4 + (threadIdx.x >> 6);
  int lane = threadIdx.x & 63;
  int tok = x[row];
  const float* e = emb + (size_t)tok * 1024;
  float v[16];
  float s = 0.f, q = 0.f;
#pragma unroll
  for (int i = 0; i < 16; ++i) { v[i] = e[lane + i * 64]; s += v[i]; q += v[i] * v[i]; }
  s = wred_sum(s); q = wred_sum(q);
  float mu = s * (1.0f / 1024.0f);
  float rstd = rsqrtf(q * (1.0f / 1024.0f) - mu * mu + 1e-5f);
  u16* hr = h16 + (size_t)row * 1024;
  u16* hnr = hn + (size_t)row * 1024;
#pragma unroll
  for (int i = 0; i < 16; ++i) {
    int d = lane + i * 64;
    hr[d] = f2bf(v[i]);
    hnr[d] = f2bf((v[i] - mu) * rstd * w[d] + b[d]);
  }
}

__global__ __launch_bounds__(256) void ln_rows(
    const u16* __restrict__ in, const float* __restrict__ w,
    const float* __restrict__ b, u16* __restrict__ out) {
  int row = blockIdx.x * 4 + (threadIdx.x >> 6);
  int lane = threadIdx.x & 63;
  const short8* ir = (const short8*)(in + (size_t)row * 1024);
  short8 c0 = ir[lane], c1 = ir[lane + 64];
  float v[16];
  float s = 0.f, q = 0.f;
#pragma unroll
  for (int j = 0; j < 8; ++j) {
    v[j] = bf2f((u16)c0[j]); v[8 + j] = bf2f((u16)c1[j]);
  }
#pragma unroll
  for (int j = 0; j < 16; ++j) { s += v[j]; q += v[j] * v[j]; }
  s = wred_sum(s); q = wred_sum(q);
  float mu = s * (1.0f / 1024.0f);
  float rstd = rsqrtf(q * (1.0f / 1024.0f) - mu * mu + 1e-5f);
  short8 o0, o1;
#pragma unroll
  for (int j = 0; j < 8; ++j) {
    int d0 = lane * 8 + j, d1 = 512 + lane * 8 + j;
    o0[j] = (short)f2bf((v[j] - mu) * rstd * w[d0] + b[d0]);
    o1[j] = (short)f2bf((v[8 + j] - mu) * rstd * w[d1] + b[d1]);
  }
  short8* orow = (short8*)(out + (size_t)row * 1024);
  orow[lane] = o0; orow[lane + 64] = o1;
}

// in-place causal softmax, column-trimmed to ceil512(i+1)
__global__ __launch_bounds__(256) void softmax_causal(u16* att) {
  int r = blockIdx.x * 4 + (threadIdx.x >> 6);
  int lane = threadIdx.x & 63;
  int i = r & 2047;
  int n = i + 1;
  int ng = (i >> 9) + 1;
  short8* pv = (short8*)(att + (size_t)r * 2048);
  float v[32];
  float m = -1e30f;
#pragma unroll
  for (int g = 0; g < 4; ++g) {
    if (g < ng) {
      short8 c = pv[g * 64 + lane];
#pragma unroll
      for (int j = 0; j < 8; ++j) {
        int idx = g * 512 + lane * 8 + j;
        float f = (idx < n) ? bf2f((u16)c[j]) : -1e30f;
        v[g * 8 + j] = f;
        m = fmaxf(m, f);
      }
    }
  }
  m = wred_max(m);
  float s = 0.f;
#pragma unroll
  for (int g = 0; g < 4; ++g) {
    if (g < ng) {
#pragma unroll
      for (int j = 0; j < 8; ++j) {
        int idx = g * 512 + lane * 8 + j;
        float e = (idx < n) ? __expf(v[g * 8 + j] - m) : 0.f;
        v[g * 8 + j] = e; s += e;
      }
    }
  }
  s = wred_sum(s);
  float inv = 1.0f / s;
#pragma unroll
  for (int g = 0; g < 4; ++g) {
    if (g < ng) {
      short8 o;
#pragma unroll
      for (int j = 0; j < 8; ++j) o[j] = (short)f2bf(v[g * 8 + j] * inv);
      pv[g * 64 + lane] = o;
    }
  }
}

// V (strided ldv) [z][2048][*] -> Vt [z][1024][2048]
__global__ __launch_bounds__(256) void transpose_v(const u16* __restrict__ V,
                                                   u16* __restrict__ Vt, int ldv) {
  int z = blockIdx.z;
  const u16* src = V + (size_t)z * 2048 * ldv;
  u16* dst = Vt + (size_t)z * 1024 * 2048;
  int j0 = (blockIdx.x >> 4) << 6;
  int d0 = (blockIdx.x & 15) << 6;
  __shared__ u16 tile[64][65];
  int c = threadIdx.x & 15;
  int rr = threadIdx.x >> 4;
#pragma unroll
  for (int q = 0; q < 4; ++q) {
    int row = rr + q * 16;
    ushort4 val = *(const ushort4*)(src + (size_t)(j0 + row) * ldv + d0 + c * 4);
    tile[row][c * 4 + 0] = val.x; tile[row][c * 4 + 1] = val.y;
    tile[row][c * 4 + 2] = val.z; tile[row][c * 4 + 3] = val.w;
  }
  __syncthreads();
#pragma unroll
  for (int q = 0; q < 4; ++q) {
    int drow = rr + q * 16;
    ushort4 o;
    o.x = tile[c * 4 + 0][drow]; o.y = tile[c * 4 + 1][drow];
    o.z = tile[c * 4 + 2][drow]; o.w = tile[c * 4 + 3][drow];
    *(ushort4*)(dst + (size_t)(d0 + drow) * 2048 + j0 + c * 4) = o;
  }
}

// final LN + logits (N=14), emb staged in padded LDS
__global__ __launch_bounds__(256) void lnf_logits(
    const u16* __restrict__ h, const float* __restrict__ w,
    const float* __restrict__ b, const float* __restrict__ emb,
    float* __restrict__ out) {
  __shared__ float el[14 * 1056];
  int t = threadIdx.x;
  for (int f = t * 4; f < 14 * 1024; f += 1024) {
    float4 e = *(const float4*)(emb + f);
    int v = f >> 10, d = f & 1023;
    float* dst = el + v * 1056 + d + (d >> 5);
    dst[0] = e.x; dst[1] = e.y; dst[2] = e.z; dst[3] = e.w;
  }
  __syncthreads();
  int lane = t & 63, wid = t >> 6;
  float w0[8], w1[8], b0[8], b1[8];
#pragma unroll
  for (int j = 0; j < 8; ++j) {
    int d0 = lane * 8 + j, d1 = 512 + lane * 8 + j;
    w0[j] = w[d0]; b0[j] = b[d0];
    w1[j] = w[d1]; b1[j] = b[d1];
  }
  const float* e0 = el + lane * 8 + (lane >> 2);
  const float* e1 = el + 528 + lane * 8 + (lane >> 2);
  for (int rr = 0; rr < 8; ++rr) {
    int row = blockIdx.x * 32 + wid * 8 + rr;
    const short8* hr = (const short8*)(h + (size_t)row * 1024);
    short8 c0 = hr[lane], c1 = hr[lane + 64];
    float v0[8], v1[8];
    float s = 0.f, q = 0.f;
#pragma unroll
    for (int j = 0; j < 8; ++j) {
      v0[j] = bf2f((u16)c0[j]); v1[j] = bf2f((u16)c1[j]);
      s += v0[j] + v1[j];
      q += v0[j] * v0[j] + v1[j] * v1[j];
    }
    s = wred_sum(s); q = wred_sum(q);
    float mu = s * (1.0f / 1024.0f);
    float rstd = rsqrtf(q * (1.0f / 1024.0f) - mu * mu + 1e-5f);
    float h0[8], h1[8];
#pragma unroll
    for (int j = 0; j < 8; ++j) {
      h0[j] = (v0[j] - mu) * rstd * w0[j] + b0[j];
      h1[j] = (v1[j] - mu) * rstd * w1[j] + b1[j];
    }
    float p[14];
#pragma unroll
    for (int v = 0; v < 14; ++v) {
      const float* ev0 = e0 + v * 1056;
      const float* ev1 = e1 + v * 1056;
      float a = 0.f;
#pragma unroll
      for (int j = 0; j < 8; ++j) a += h0[j] * ev0[j] + h1[j] * ev1[j];
      p[v] = a;
    }
#pragma unroll
    for (int m = 32; m; m >>= 1)
#pragma unroll
      for (int v = 0; v < 14; ++v) p[v] += __shfl_xor(p[v], m, 64);
    if (lane == 0) {
      float* orow = out + (size_t)row * 14;
#pragma unroll
      for (int v = 0; v < 14; ++v) orow[v] = p[v];
    }
  }
}

__global__ void zero_out_k(float* o, int n) {
  int i = blockIdx.x * 256 + threadIdx.x;
  if (i < n) o[i] = 0.f;
}
__global__ void diag_k(float* o, float v) { if (threadIdx.x == 0) o[0] = v; }

// ---------------------------------------------------------------------------
extern "C" void kernel_launch(void* const* d_in, const int* in_sizes, int n_in,
                              void* d_out, int out_size, void* d_ws, size_t ws_size,
                              hipStream_t stream) {
  const int* x = (const int*)d_in[0];
  const float* tok_emb = (const float*)d_in[1];
  const float* ln1_w = (const float*)d_in[2];
  const float* ln1_b = (const float*)d_in[3];
  const float* qw = (const float*)d_in[4];
  const float* qb = (const float*)d_in[5];
  const float* kw = (const float*)d_in[6];
  const float* kb = (const float*)d_in[7];
  const float* vw = (const float*)d_in[8];
  const float* vb = (const float*)d_in[9];
  const float* pw = (const float*)d_in[10];
  const float* pb = (const float*)d_in[11];
  const float* ln2_w = (const float*)d_in[12];
  const float* ln2_b = (const float*)d_in[13];
  const float* f1w = (const float*)d_in[14];
  const float* f1b = (const float*)d_in[15];
  const float* f2w = (const float*)d_in[16];
  const float* f2b = (const float*)d_in[17];
  const float* lnf_w = (const float*)d_in[18];
  const float* lnf_b = (const float*)d_in[19];
  float* out = (float*)d_out;

  const long long T = 16384, D = 1024, F = 4096, S = 2048;
  const size_t MB = 1ull << 20;
  char* base = (char*)d_ws;

  if (ws_size < 224 * MB) {
    zero_out_k<<<dim3((out_size + 255) / 256), 256, 0, stream>>>(out, out_size);
    diag_k<<<dim3(1), 1, 0, stream>>>(out, (float)ws_size);
    return;
  }

  // ---- 224 MB phase-multiplexed layout ----
  u16* rA16 = (u16*)base;                  // 0..32MB   residual bf16
  u16* rB   = (u16*)(base + 32 * MB);      // 32..64MB  normalized / Vt
  u16* QKV  = (u16*)(base + 64 * MB);      // 64..160MB [16384][3072] / CB
  u16* SC   = (u16*)(base + 160 * MB);     // 160..224MB W3+qkvb -> scores -> PW
  u16* W3   = SC;                          // [3072][1024] bf16 (6MB)
  float* qkvb = (float*)(base + 166 * MB); // 12KB
  u16* PW  = SC;                           // pw bf16 (2MB), post-PV
  u16* CB  = QKV;                          // [16384][4096] bf16, FFN
  u16* F1  = (u16*)(base + 192 * MB);      // [4096][1024] (8MB)
  u16* F2  = (u16*)(base + 200 * MB);      // [1024][4096] (8MB)

  auto cvt = [&](const float* src, u16* dst, long long n) {
    int n4 = (int)(n / 4);
    f32_to_bf16_v4<<<dim3((n4 + 255) / 256), dim3(256), 0, stream>>>(src, dst, n4);
  };
  auto gemm = [&](const u16* A, const u16* B, u16* C, const float* bias,
                  const u16* res, long long M, long long N, long long K,
                  long long lda, long long ldb, long long ldc, float alpha,
                  int flags, long long sA, long long sB, long long sC,
                  int gx, int gz) {
    gemm128<<<dim3(gx, 1, gz), dim3(256), 0, stream>>>(
        A, B, C, bias, res, (int)M, (int)N, (int)K, (int)lda, (int)ldb,
        (int)ldc, alpha, flags, sA, sB, sC);
  };

  // phase 0: fused QKV weights + biases into SC region (dead until scores)
  cvt(qw, W3, D * D);
  cvt(kw, W3 + 1024 * 1024, D * D);
  cvt(vw, W3 + 2 * 1024 * 1024, D * D);
  hipMemcpyAsync(qkvb, qb, D * 4, hipMemcpyDeviceToDevice, stream);
  hipMemcpyAsync(qkvb + 1024, kb, D * 4, hipMemcpyDeviceToDevice, stream);
  hipMemcpyAsync(qkvb + 2048, vb, D * 4, hipMemcpyDeviceToDevice, stream);

  embed_ln1<<<dim3(T / 4), 256, 0, stream>>>(x, tok_emb, ln1_w, ln1_b, rA16, rB);

  // fused QKV projection: [16384][3072]  grid 128x24
  gemm(rB, W3, QKV, qkvb, nullptr, T, 3072, D, D, D, 3072, 1.f, FLAG_BIAS,
       0, 0, 0, 3072, 1);

  // scores = (Q K^T)/32, flat causal triangle (136 blocks x 8 batches)
  gemm(QKV, QKV + 1024, SC, nullptr, nullptr, S, S, D, 3072, 3072, 2048,
       0.03125f, FLAG_TRI, S * 3072, S * 3072, S * S, 1088, 1);

  // V^T per batch into rB (rB dead after QKV gemm)
  transpose_v<<<dim3(512, 1, 8), 256, 0, stream>>>(QKV + 2048, rB, 3072);

  softmax_causal<<<dim3(T / 4), 256, 0, stream>>>(SC);

  // attn out = P @ V^T, causal K-limit, into dead Q columns (16x8 grid x8)
  gemm(SC, rB, QKV, nullptr, nullptr, S, D, S, S, S, 3072, 1.f, FLAG_CK,
       S * S, D * S, S * 3072, 128, 8);

  // out-proj + residual (scores dead -> PW at SC)
  cvt(pw, PW, D * D);
  gemm(QKV, PW, rA16, pb, rA16, T, D, D, 3072, D, D, 1.f, FLAG_BIAS | FLAG_RES,
       0, 0, 0, 1024, 1);

  ln_rows<<<dim3(T / 4), 256, 0, stream>>>(rA16, ln2_w, ln2_b, rB);

  // FFN single-pass: CB [16384][4096] over dead QKV region
  cvt(f1w, F1, F * D);
  cvt(f2w, F2, D * F);
  gemm(rB, F1, CB, f1b, nullptr, T, F, D, D, D, F, 1.f, FLAG_BIAS | FLAG_GELU,
       0, 0, 0, 4096, 1);
  gemm(CB, F2, rA16, f2b, rA16, T, D, F, F, F, D, 1.f, FLAG_BIAS | FLAG_RES,
       0, 0, 0, 1024, 1);

  lnf_logits<<<dim3(512), 256, 0, stream>>>(rA16, lnf_w, lnf_b, tok_emb, out);
}